// Round 3
// baseline (732.120 us; speedup 1.0000x reference)
//
#include <hip/hip_runtime.h>
#include <hip/hip_bf16.h>
#include <cstdint>

#define B 2
#define NH 4
#define HD 32
#define DIM 128
#define CX 256
#define CY 512
#define PX 4096
#define PY 1024
#define QKV 384
#define GAMMA 0.17677669529663687f

typedef unsigned short u16;
typedef unsigned int u32;

__device__ __forceinline__ float bf2f(u32 h) {
  union { u32 u; float f; } v; v.u = (h & 0xffffu) << 16; return v.f;
}
__device__ __forceinline__ u16 f2bf(float f) {
  u32 u = __float_as_uint(f);
  u32 r = (u + 0x7fffu + ((u >> 16) & 1u)) >> 16;
  return (u16)r;
}

// input element counts (compile-time)
#define N_X   (B * CX * PX)      // 2,097,152
#define N_Y   (B * CY * PY)      // 1,048,576
#define N_WX  (QKV * CX)         // 98,304
#define N_BX  (QKV)              // 384
#define N_WY  (QKV * CY)         // 196,608
#define N_BY  (QKV)              // 384
#define N_WPX (CX * DIM)         // 32,768
#define N_BPX (CX)               // 256
#define N_WPY (CY * DIM)         // 65,536
#define N_BPY (CY)               // 512

// ---- workspace layout (u16 element offsets), all segments 16B-aligned ----
enum : size_t {
  OFF_FLAGS = 0,                         // 32 u16 = 16 ints
  OFF_CXB   = 32,
  OFF_CYB   = OFF_CXB  + N_X,
  OFF_CWX   = OFF_CYB  + N_Y,
  OFF_CBX   = OFF_CWX  + N_WX,
  OFF_CWY   = OFF_CBX  + N_BX,
  OFF_CBY   = OFF_CWY  + N_WY,
  OFF_CWPX  = OFF_CBY  + N_BY,
  OFF_CBPX  = OFF_CWPX + N_WPX,
  OFF_CWPY  = OFF_CBPX + N_BPX,
  OFF_CBPY  = OFF_CWPY + N_WPY,
  OFF_QKVX  = OFF_CBPY + N_BPY,          // [B][QKV][PX] bf16
  OFF_QKVY  = OFF_QKVX + (size_t)B * QKV * PX,  // [B][QKV][PY] bf16
  WS_END    = OFF_QKVY + (size_t)B * QKV * PY,  // ~14.95 MB
};

// ---- per-tensor dtype detection ----
// Examine u16s at EVEN indices < n_elem (exist in both worlds). Genuine bf16
// data (|v| <= ~8) never has exponent >= 140 (|v| >= 2^13). f32 data's low
// mantissa halves are ~uniform bits -> ~45% have exponent >= 140.
__global__ void k_detect(const u16* x, const u16* y, const u16* wx, const u16* bx,
                         const u16* wy, const u16* by, const u16* wpx, const u16* bpx,
                         const u16* wpy, const u16* bpy, int* flags) {
  const u16* p; int n;
  switch (blockIdx.x) {
    case 0: p = x;   n = N_X;   break;
    case 1: p = y;   n = N_Y;   break;
    case 2: p = wx;  n = N_WX;  break;
    case 3: p = bx;  n = N_BX;  break;
    case 4: p = wy;  n = N_WY;  break;
    case 5: p = by;  n = N_BY;  break;
    case 6: p = wpx; n = N_WPX; break;
    case 7: p = bpx; n = N_BPX; break;
    case 8: p = wpy; n = N_WPY; break;
    default: p = bpy; n = N_BPY; break;
  }
  int ncheck = n / 2; if (ncheck > 4096) ncheck = 4096;
  int cnt = 0;
  for (int i = threadIdx.x; i < ncheck; i += 256) {
    u32 u = p[2 * i];
    if ((u & 0x7F80u) >= 0x4600u) cnt++;
  }
  __shared__ int red[256];
  red[threadIdx.x] = cnt;
  __syncthreads();
  for (int s = 128; s > 0; s >>= 1) {
    if ((int)threadIdx.x < s) red[threadIdx.x] += red[threadIdx.x + s];
    __syncthreads();
  }
  if (threadIdx.x == 0) flags[blockIdx.x] = (red[0] * 4 >= ncheck) ? 1 : 0;
}

// ---- normalize every input to a bf16 copy in ws ----
__global__ void k_convert(const void* x, const void* y, const void* wx, const void* bx,
                          const void* wy, const void* by, const void* wpx, const void* bpx,
                          const void* wpy, const void* bpy,
                          u16* __restrict__ ws, const int* __restrict__ flags) {
  const void* src; size_t dstoff; int n;
  switch (blockIdx.y) {
    case 0: src = x;   dstoff = OFF_CXB;  n = N_X;   break;
    case 1: src = y;   dstoff = OFF_CYB;  n = N_Y;   break;
    case 2: src = wx;  dstoff = OFF_CWX;  n = N_WX;  break;
    case 3: src = bx;  dstoff = OFF_CBX;  n = N_BX;  break;
    case 4: src = wy;  dstoff = OFF_CWY;  n = N_WY;  break;
    case 5: src = by;  dstoff = OFF_CBY;  n = N_BY;  break;
    case 6: src = wpx; dstoff = OFF_CWPX; n = N_WPX; break;
    case 7: src = bpx; dstoff = OFF_CBPX; n = N_BPX; break;
    case 8: src = wpy; dstoff = OFF_CWPY; n = N_WPY; break;
    default: src = bpy; dstoff = OFF_CBPY; n = N_BPY; break;
  }
  int e0 = (blockIdx.x * 256 + threadIdx.x) * 8;
  if (e0 >= n) return;
  u16* dst = ws + dstoff + e0;
  if (flags[blockIdx.y]) {
    const float* s = (const float*)src + e0;
    float4 a = *(const float4*)s;
    float4 bq = *(const float4*)(s + 4);
    ushort4 o0, o1;
    o0.x = f2bf(a.x);  o0.y = f2bf(a.y);  o0.z = f2bf(a.z);  o0.w = f2bf(a.w);
    o1.x = f2bf(bq.x); o1.y = f2bf(bq.y); o1.z = f2bf(bq.z); o1.w = f2bf(bq.w);
    *(ushort4*)dst = o0;
    *(ushort4*)(dst + 4) = o1;
  } else {
    uint4 v = *(const uint4*)((const u16*)src + e0);
    *(uint4*)dst = v;
  }
}

// ---- qkv GEMM: out[b][o][p] = bias[o] + sum_c W[o][c] * X[b][c][p] ----
// all bf16 I/O, f32 accumulate. W transposed on the fly through LDS.
// tile 128(o) x 128(p), K-tile 32; block 256 = (tx 16) x (ty 16); 8x8/thread
__global__ __launch_bounds__(256) void k_qkv(
    const u16* __restrict__ X, const u16* __restrict__ W,
    const u16* __restrict__ bias, u16* __restrict__ out,
    int C, int P) {
  __shared__ float lX[32][132];
  __shared__ float lW[32][132];
  const int t = threadIdx.x;
  const int tx = t & 15, ty = t >> 4;
  const int p0 = blockIdx.x * 128, o0 = blockIdx.y * 128, b = blockIdx.z;

  float acc[8][8];
#pragma unroll
  for (int i = 0; i < 8; i++) {
    float bv = bf2f(bias[o0 + (i >> 2) * 64 + ty * 4 + (i & 3)]);
#pragma unroll
    for (int j = 0; j < 8; j++) acc[i][j] = bv;
  }

  for (int c0 = 0; c0 < C; c0 += 32) {
    __syncthreads();
#pragma unroll
    for (int chh = 0; chh < 2; chh++) {
      int chunk = t + chh * 256;
      {
        int cl = chunk >> 4, el = (chunk & 15) * 8;
        uint4 u = *(const uint4*)&X[((size_t)b * C + c0 + cl) * P + p0 + el];
        float* dx = &lX[cl][el];
        dx[0] = bf2f(u.x); dx[1] = bf2f(u.x >> 16);
        dx[2] = bf2f(u.y); dx[3] = bf2f(u.y >> 16);
        dx[4] = bf2f(u.z); dx[5] = bf2f(u.z >> 16);
        dx[6] = bf2f(u.w); dx[7] = bf2f(u.w >> 16);
      }
      {
        int ol = chunk >> 2, c8 = (chunk & 3) * 8;
        uint4 w = *(const uint4*)&W[(size_t)(o0 + ol) * C + c0 + c8];
        lW[c8 + 0][ol] = bf2f(w.x); lW[c8 + 1][ol] = bf2f(w.x >> 16);
        lW[c8 + 2][ol] = bf2f(w.y); lW[c8 + 3][ol] = bf2f(w.y >> 16);
        lW[c8 + 4][ol] = bf2f(w.z); lW[c8 + 5][ol] = bf2f(w.z >> 16);
        lW[c8 + 6][ol] = bf2f(w.w); lW[c8 + 7][ol] = bf2f(w.w >> 16);
      }
    }
    __syncthreads();
#pragma unroll
    for (int c = 0; c < 32; c++) {
      float4 xa = *(const float4*)&lX[c][tx * 4];
      float4 xb = *(const float4*)&lX[c][64 + tx * 4];
      float4 wa = *(const float4*)&lW[c][ty * 4];
      float4 wb = *(const float4*)&lW[c][64 + ty * 4];
      float xv[8] = {xa.x, xa.y, xa.z, xa.w, xb.x, xb.y, xb.z, xb.w};
      float wv[8] = {wa.x, wa.y, wa.z, wa.w, wb.x, wb.y, wb.z, wb.w};
#pragma unroll
      for (int i = 0; i < 8; i++)
#pragma unroll
        for (int j = 0; j < 8; j++)
          acc[i][j] = fmaf(wv[i], xv[j], acc[i][j]);
    }
  }

#pragma unroll
  for (int i = 0; i < 8; i++) {
    int o = o0 + (i >> 2) * 64 + ty * 4 + (i & 3);
    u16* ob = &out[((size_t)b * QKV + o) * P + p0];
    ushort4 s0, s1;
    s0.x = f2bf(acc[i][0]); s0.y = f2bf(acc[i][1]);
    s0.z = f2bf(acc[i][2]); s0.w = f2bf(acc[i][3]);
    s1.x = f2bf(acc[i][4]); s1.y = f2bf(acc[i][5]);
    s1.z = f2bf(acc[i][6]); s1.w = f2bf(acc[i][7]);
    *(ushort4*)&ob[tx * 4] = s0;
    *(ushort4*)&ob[64 + tx * 4] = s1;
  }
}

// ---- proj GEMM + bias + residual; store dtype per flags[0] ----
__global__ __launch_bounds__(256) void k_proj(
    const u16* __restrict__ A, const u16* __restrict__ W,
    const u16* __restrict__ bias, const u16* __restrict__ res,
    void* __restrict__ outv, size_t out_off, const int* __restrict__ flags,
    int P, int OT) {
  __shared__ float lX[32][132];
  __shared__ float lW[32][132];
  const int t = threadIdx.x;
  const int tx = t & 15, ty = t >> 4;
  const int p0 = blockIdx.x * 128, o0 = blockIdx.y * 128, b = blockIdx.z;

  float acc[8][8];
#pragma unroll
  for (int i = 0; i < 8; i++) {
    float bv = bf2f(bias[o0 + (i >> 2) * 64 + ty * 4 + (i & 3)]);
#pragma unroll
    for (int j = 0; j < 8; j++) acc[i][j] = bv;
  }

  for (int c0 = 0; c0 < DIM; c0 += 32) {
    __syncthreads();
#pragma unroll
    for (int chh = 0; chh < 2; chh++) {
      int chunk = t + chh * 256;
      {
        int cl = chunk >> 4, el = (chunk & 15) * 8;
        uint4 u = *(const uint4*)&A[((size_t)b * QKV + c0 + cl) * P + p0 + el];
        float* dx = &lX[cl][el];
        dx[0] = bf2f(u.x); dx[1] = bf2f(u.x >> 16);
        dx[2] = bf2f(u.y); dx[3] = bf2f(u.y >> 16);
        dx[4] = bf2f(u.z); dx[5] = bf2f(u.z >> 16);
        dx[6] = bf2f(u.w); dx[7] = bf2f(u.w >> 16);
      }
      {
        int ol = chunk >> 2, c8 = (chunk & 3) * 8;
        uint4 w = *(const uint4*)&W[(size_t)(o0 + ol) * DIM + c0 + c8];
        lW[c8 + 0][ol] = bf2f(w.x); lW[c8 + 1][ol] = bf2f(w.x >> 16);
        lW[c8 + 2][ol] = bf2f(w.y); lW[c8 + 3][ol] = bf2f(w.y >> 16);
        lW[c8 + 4][ol] = bf2f(w.z); lW[c8 + 5][ol] = bf2f(w.z >> 16);
        lW[c8 + 6][ol] = bf2f(w.w); lW[c8 + 7][ol] = bf2f(w.w >> 16);
      }
    }
    __syncthreads();
#pragma unroll
    for (int c = 0; c < 32; c++) {
      float4 xa = *(const float4*)&lX[c][tx * 4];
      float4 xb = *(const float4*)&lX[c][64 + tx * 4];
      float4 wa = *(const float4*)&lW[c][ty * 4];
      float4 wb = *(const float4*)&lW[c][64 + ty * 4];
      float xv[8] = {xa.x, xa.y, xa.z, xa.w, xb.x, xb.y, xb.z, xb.w};
      float wv[8] = {wa.x, wa.y, wa.z, wa.w, wb.x, wb.y, wb.z, wb.w};
#pragma unroll
      for (int i = 0; i < 8; i++)
#pragma unroll
        for (int j = 0; j < 8; j++)
          acc[i][j] = fmaf(wv[i], xv[j], acc[i][j]);
    }
  }

  const bool f32out = (flags[0] != 0);
#pragma unroll
  for (int i = 0; i < 8; i++) {
    int o = o0 + (i >> 2) * 64 + ty * 4 + (i & 3);
    size_t base = ((size_t)b * OT + o) * P + p0;
#pragma unroll
    for (int part = 0; part < 2; part++) {
      int p = part * 64 + tx * 4;
      ushort4 r = *(const ushort4*)&res[base + p];
      float v0 = acc[i][part * 4 + 0] + bf2f(r.x);
      float v1 = acc[i][part * 4 + 1] + bf2f(r.y);
      float v2 = acc[i][part * 4 + 2] + bf2f(r.z);
      float v3 = acc[i][part * 4 + 3] + bf2f(r.w);
      if (f32out) {
        float* of = (float*)outv + out_off;
        *(float4*)&of[base + p] = make_float4(v0, v1, v2, v3);
      } else {
        u16* ob = (u16*)outv + out_off;
        ushort4 w;
        w.x = f2bf(v0); w.y = f2bf(v1); w.z = f2bf(v2); w.w = f2bf(v3);
        *(ushort4*)&ob[base + p] = w;
      }
    }
  }
}

// ---- flash-style attention (vector ALU, f32 in LDS/regs, bf16 global) ----
// grid: (Pq/64, NH, B). block 256 = (tx 16: keys/dims) x (ty 16: queries).
// Output written into the q-channel region of qkvq (alias; safe: Q read to
// LDS first; other attn kernel reads only k/v channels; proj runs after).
__global__ __launch_bounds__(256) void k_attn(
    u16* __restrict__ qkvq, const u16* __restrict__ qkvkv,
    int Pq, int Pk) {
  __shared__ float lQ[32][68];
  __shared__ float lK[32][68];
  __shared__ float lV[32][68];
  __shared__ float lP[64][68];
  const int t = threadIdx.x, tx = t & 15, ty = t >> 4;
  const int p0 = blockIdx.x * 64;
  const int h = blockIdx.y, b = blockIdx.z;
  u16* qb = qkvq + ((size_t)b * QKV + h * HD) * Pq;
  const u16* kb = qkvkv + ((size_t)b * QKV + DIM + h * HD) * Pk;
  const u16* vb = qkvkv + ((size_t)b * QKV + 2 * DIM + h * HD) * Pk;

#pragma unroll
  for (int chh = 0; chh < 2; chh++) {
    int id = t + chh * 256;
    int d = id >> 4, q4 = (id & 15) * 4;
    uint2 v = *(const uint2*)&qb[(size_t)d * Pq + p0 + q4];
    lQ[d][q4 + 0] = bf2f(v.x) * GAMMA;
    lQ[d][q4 + 1] = bf2f(v.x >> 16) * GAMMA;
    lQ[d][q4 + 2] = bf2f(v.y) * GAMMA;
    lQ[d][q4 + 3] = bf2f(v.y >> 16) * GAMMA;
  }

  float m_run[4], l_run[4], oa[4][2];
#pragma unroll
  for (int i = 0; i < 4; i++) { m_run[i] = -1e30f; l_run[i] = 0.f; oa[i][0] = 0.f; oa[i][1] = 0.f; }

  for (int k0 = 0; k0 < Pk; k0 += 64) {
    __syncthreads();
#pragma unroll
    for (int chh = 0; chh < 2; chh++) {
      int id = t + chh * 256;
      int d = id >> 4, k4 = (id & 15) * 4;
      uint2 kv = *(const uint2*)&kb[(size_t)d * Pk + k0 + k4];
      lK[d][k4 + 0] = bf2f(kv.x); lK[d][k4 + 1] = bf2f(kv.x >> 16);
      lK[d][k4 + 2] = bf2f(kv.y); lK[d][k4 + 3] = bf2f(kv.y >> 16);
      uint2 vv = *(const uint2*)&vb[(size_t)d * Pk + k0 + k4];
      lV[d][k4 + 0] = bf2f(vv.x); lV[d][k4 + 1] = bf2f(vv.x >> 16);
      lV[d][k4 + 2] = bf2f(vv.y); lV[d][k4 + 3] = bf2f(vv.y >> 16);
    }
    __syncthreads();

    float s[4][4];
#pragma unroll
    for (int i = 0; i < 4; i++)
#pragma unroll
      for (int j = 0; j < 4; j++) s[i][j] = 0.f;

#pragma unroll
    for (int d = 0; d < 32; d++) {
      float4 q = *(const float4*)&lQ[d][ty * 4];
      float4 k = *(const float4*)&lK[d][tx * 4];
      float qv[4] = {q.x, q.y, q.z, q.w};
      float kv[4] = {k.x, k.y, k.z, k.w};
#pragma unroll
      for (int i = 0; i < 4; i++)
#pragma unroll
        for (int j = 0; j < 4; j++)
          s[i][j] = fmaf(qv[i], kv[j], s[i][j]);
    }

#pragma unroll
    for (int i = 0; i < 4; i++) {
      float ml = fmaxf(fmaxf(s[i][0], s[i][1]), fmaxf(s[i][2], s[i][3]));
#pragma unroll
      for (int off = 1; off < 16; off <<= 1) ml = fmaxf(ml, __shfl_xor(ml, off));
      float mnew = fmaxf(m_run[i], ml);
      float alpha = __expf(m_run[i] - mnew);
      float e0 = __expf(s[i][0] - mnew);
      float e1 = __expf(s[i][1] - mnew);
      float e2 = __expf(s[i][2] - mnew);
      float e3 = __expf(s[i][3] - mnew);
      float ls = e0 + e1 + e2 + e3;
#pragma unroll
      for (int off = 1; off < 16; off <<= 1) ls += __shfl_xor(ls, off);
      l_run[i] = l_run[i] * alpha + ls;
      m_run[i] = mnew;
      oa[i][0] *= alpha; oa[i][1] *= alpha;
      float4 pv = make_float4(e0, e1, e2, e3);
      *(float4*)&lP[ty * 4 + i][tx * 4] = pv;
    }
    __syncthreads();

    const int d0 = tx * 2, d1 = d0 + 1;
#pragma unroll
    for (int k4 = 0; k4 < 64; k4 += 4) {
      float4 va = *(const float4*)&lV[d0][k4];
      float4 vbv = *(const float4*)&lV[d1][k4];
#pragma unroll
      for (int i = 0; i < 4; i++) {
        float4 p = *(const float4*)&lP[ty * 4 + i][k4];
        oa[i][0] = fmaf(p.x, va.x, fmaf(p.y, va.y, fmaf(p.z, va.z, fmaf(p.w, va.w, oa[i][0]))));
        oa[i][1] = fmaf(p.x, vbv.x, fmaf(p.y, vbv.y, fmaf(p.z, vbv.z, fmaf(p.w, vbv.w, oa[i][1]))));
      }
    }
  }

#pragma unroll
  for (int i = 0; i < 4; i++) {
    float inv = 1.0f / l_run[i];
    int q = p0 + ty * 4 + i;
    qb[(size_t)(tx * 2) * Pq + q] = f2bf(oa[i][0] * inv);
    qb[(size_t)(tx * 2 + 1) * Pq + q] = f2bf(oa[i][1] * inv);
  }
}

extern "C" void kernel_launch(void* const* d_in, const int* in_sizes, int n_in,
                              void* d_out, int out_size, void* d_ws, size_t ws_size,
                              hipStream_t stream) {
  (void)in_sizes; (void)n_in; (void)out_size; (void)ws_size;
  u16* ws = (u16*)d_ws;
  int* flags = (int*)(ws + OFF_FLAGS);
  u16* cx   = ws + OFF_CXB;
  u16* cy   = ws + OFF_CYB;
  u16* cwx  = ws + OFF_CWX;
  u16* cbx  = ws + OFF_CBX;
  u16* cwy  = ws + OFF_CWY;
  u16* cby  = ws + OFF_CBY;
  u16* cwpx = ws + OFF_CWPX;
  u16* cbpx = ws + OFF_CBPX;
  u16* cwpy = ws + OFF_CWPY;
  u16* cbpy = ws + OFF_CBPY;
  u16* qkvx = ws + OFF_QKVX;
  u16* qkvy = ws + OFF_QKVY;

  // 0. detect per-tensor dtype, then normalize everything to bf16 in ws
  k_detect<<<dim3(10), 256, 0, stream>>>(
      (const u16*)d_in[0], (const u16*)d_in[1], (const u16*)d_in[2], (const u16*)d_in[3],
      (const u16*)d_in[4], (const u16*)d_in[5], (const u16*)d_in[6], (const u16*)d_in[7],
      (const u16*)d_in[8], (const u16*)d_in[9], flags);
  k_convert<<<dim3(1024, 10), 256, 0, stream>>>(
      d_in[0], d_in[1], d_in[2], d_in[3], d_in[4], d_in[5], d_in[6], d_in[7],
      d_in[8], d_in[9], ws, flags);

  // 1. qkv GEMMs (bf16 out)
  k_qkv<<<dim3(PX / 128, 3, B), 256, 0, stream>>>(cx, cwx, cbx, qkvx, CX, PX);
  k_qkv<<<dim3(PY / 128, 3, B), 256, 0, stream>>>(cy, cwy, cby, qkvy, CY, PY);
  // 2. attention: x attends to y; y attends to x. Output aliases q region.
  k_attn<<<dim3(PX / 64, NH, B), 256, 0, stream>>>(qkvx, qkvy, PX, PY);
  k_attn<<<dim3(PY / 64, NH, B), 256, 0, stream>>>(qkvy, qkvx, PY, PX);
  // 3. proj + bias + residual -> out (dtype per flags[0])
  k_proj<<<dim3(PX / 128, CX / 128, B), 256, 0, stream>>>(
      qkvx, cwpx, cbpx, cx, d_out, 0, flags, PX, CX);
  k_proj<<<dim3(PY / 128, CY / 128, B), 256, 0, stream>>>(
      qkvy, cwpy, cbpy, cy, d_out, (size_t)B * CX * PX, flags, PY, CY);
}

// Round 4
// 346.814 us; speedup vs baseline: 2.1110x; 2.1110x over previous
//
#include <hip/hip_runtime.h>
#include <hip/hip_bf16.h>
#include <cstdint>

#define B 2
#define NH 4
#define HD 32
#define DIM 128
#define CX 256
#define CY 512
#define PX 4096
#define PY 1024
#define QKV 384
#define GAMMA 0.17677669529663687f

typedef unsigned short u16;
typedef unsigned int u32;

using short8 = __attribute__((ext_vector_type(8))) short;
using f32x4  = __attribute__((ext_vector_type(4))) float;

__device__ __forceinline__ float bf2f(u32 h) {
  union { u32 u; float f; } v; v.u = (h & 0xffffu) << 16; return v.f;
}
__device__ __forceinline__ u16 f2bf(float f) {
  u32 u = __float_as_uint(f);
  u32 r = (u + 0x7fffu + ((u >> 16) & 1u)) >> 16;
  return (u16)r;
}

// input element counts (compile-time)
#define N_X   (B * CX * PX)
#define N_Y   (B * CY * PY)
#define N_WX  (QKV * CX)
#define N_BX  (QKV)
#define N_WY  (QKV * CY)
#define N_BY  (QKV)
#define N_WPX (CX * DIM)
#define N_BPX (CX)
#define N_WPY (CY * DIM)
#define N_BPY (CY)

// ---- workspace layout (u16 element offsets) ----
enum : size_t {
  OFF_FLAGS = 0,
  OFF_CXB   = 32,
  OFF_CYB   = OFF_CXB  + N_X,
  OFF_CWX   = OFF_CYB  + N_Y,
  OFF_CBX   = OFF_CWX  + N_WX,
  OFF_CWY   = OFF_CBX  + N_BX,
  OFF_CBY   = OFF_CWY  + N_WY,
  OFF_CWPX  = OFF_CBY  + N_BY,
  OFF_CBPX  = OFF_CWPX + N_WPX,
  OFF_CWPY  = OFF_CBPX + N_BPX,
  OFF_CBPY  = OFF_CWPY + N_WPY,
  OFF_QKVX  = OFF_CBPY + N_BPY,
  OFF_QKVY  = OFF_QKVX + (size_t)B * QKV * PX,
  WS_END    = OFF_QKVY + (size_t)B * QKV * PY,
};

// ---- per-tensor dtype detection (bf16 vs f32) ----
__global__ void k_detect(const u16* x, const u16* y, const u16* wx, const u16* bx,
                         const u16* wy, const u16* by, const u16* wpx, const u16* bpx,
                         const u16* wpy, const u16* bpy, int* flags) {
  const u16* p; int n;
  switch (blockIdx.x) {
    case 0: p = x;   n = N_X;   break;
    case 1: p = y;   n = N_Y;   break;
    case 2: p = wx;  n = N_WX;  break;
    case 3: p = bx;  n = N_BX;  break;
    case 4: p = wy;  n = N_WY;  break;
    case 5: p = by;  n = N_BY;  break;
    case 6: p = wpx; n = N_WPX; break;
    case 7: p = bpx; n = N_BPX; break;
    case 8: p = wpy; n = N_WPY; break;
    default: p = bpy; n = N_BPY; break;
  }
  int ncheck = n / 2; if (ncheck > 4096) ncheck = 4096;
  int cnt = 0;
  for (int i = threadIdx.x; i < ncheck; i += 256) {
    u32 u = p[2 * i];
    if ((u & 0x7F80u) >= 0x4600u) cnt++;
  }
  __shared__ int red[256];
  red[threadIdx.x] = cnt;
  __syncthreads();
  for (int s = 128; s > 0; s >>= 1) {
    if ((int)threadIdx.x < s) red[threadIdx.x] += red[threadIdx.x + s];
    __syncthreads();
  }
  if (threadIdx.x == 0) flags[blockIdx.x] = (red[0] * 4 >= ncheck) ? 1 : 0;
}

// ---- normalize every input to a bf16 copy in ws ----
__global__ void k_convert(const void* x, const void* y, const void* wx, const void* bx,
                          const void* wy, const void* by, const void* wpx, const void* bpx,
                          const void* wpy, const void* bpy,
                          u16* __restrict__ ws, const int* __restrict__ flags) {
  const void* src; size_t dstoff; int n;
  switch (blockIdx.y) {
    case 0: src = x;   dstoff = OFF_CXB;  n = N_X;   break;
    case 1: src = y;   dstoff = OFF_CYB;  n = N_Y;   break;
    case 2: src = wx;  dstoff = OFF_CWX;  n = N_WX;  break;
    case 3: src = bx;  dstoff = OFF_CBX;  n = N_BX;  break;
    case 4: src = wy;  dstoff = OFF_CWY;  n = N_WY;  break;
    case 5: src = by;  dstoff = OFF_CBY;  n = N_BY;  break;
    case 6: src = wpx; dstoff = OFF_CWPX; n = N_WPX; break;
    case 7: src = bpx; dstoff = OFF_CBPX; n = N_BPX; break;
    case 8: src = wpy; dstoff = OFF_CWPY; n = N_WPY; break;
    default: src = bpy; dstoff = OFF_CBPY; n = N_BPY; break;
  }
  int e0 = (blockIdx.x * 256 + threadIdx.x) * 8;
  if (e0 >= n) return;
  u16* dst = ws + dstoff + e0;
  if (flags[blockIdx.y]) {
    const float* s = (const float*)src + e0;
    float4 a = *(const float4*)s;
    float4 bq = *(const float4*)(s + 4);
    ushort4 o0, o1;
    o0.x = f2bf(a.x);  o0.y = f2bf(a.y);  o0.z = f2bf(a.z);  o0.w = f2bf(a.w);
    o1.x = f2bf(bq.x); o1.y = f2bf(bq.y); o1.z = f2bf(bq.z); o1.w = f2bf(bq.w);
    *(ushort4*)dst = o0;
    *(ushort4*)(dst + 4) = o1;
  } else {
    uint4 v = *(const uint4*)((const u16*)src + e0);
    *(uint4*)dst = v;
  }
}

// ---- qkv GEMM (vector ALU, unchanged from passing R3) ----
__global__ __launch_bounds__(256) void k_qkv(
    const u16* __restrict__ X, const u16* __restrict__ W,
    const u16* __restrict__ bias, u16* __restrict__ out,
    int C, int P) {
  __shared__ float lX[32][132];
  __shared__ float lW[32][132];
  const int t = threadIdx.x;
  const int tx = t & 15, ty = t >> 4;
  const int p0 = blockIdx.x * 128, o0 = blockIdx.y * 128, b = blockIdx.z;

  float acc[8][8];
#pragma unroll
  for (int i = 0; i < 8; i++) {
    float bv = bf2f(bias[o0 + (i >> 2) * 64 + ty * 4 + (i & 3)]);
#pragma unroll
    for (int j = 0; j < 8; j++) acc[i][j] = bv;
  }

  for (int c0 = 0; c0 < C; c0 += 32) {
    __syncthreads();
#pragma unroll
    for (int chh = 0; chh < 2; chh++) {
      int chunk = t + chh * 256;
      {
        int cl = chunk >> 4, el = (chunk & 15) * 8;
        uint4 u = *(const uint4*)&X[((size_t)b * C + c0 + cl) * P + p0 + el];
        float* dx = &lX[cl][el];
        dx[0] = bf2f(u.x); dx[1] = bf2f(u.x >> 16);
        dx[2] = bf2f(u.y); dx[3] = bf2f(u.y >> 16);
        dx[4] = bf2f(u.z); dx[5] = bf2f(u.z >> 16);
        dx[6] = bf2f(u.w); dx[7] = bf2f(u.w >> 16);
      }
      {
        int ol = chunk >> 2, c8 = (chunk & 3) * 8;
        uint4 w = *(const uint4*)&W[(size_t)(o0 + ol) * C + c0 + c8];
        lW[c8 + 0][ol] = bf2f(w.x); lW[c8 + 1][ol] = bf2f(w.x >> 16);
        lW[c8 + 2][ol] = bf2f(w.y); lW[c8 + 3][ol] = bf2f(w.y >> 16);
        lW[c8 + 4][ol] = bf2f(w.z); lW[c8 + 5][ol] = bf2f(w.z >> 16);
        lW[c8 + 6][ol] = bf2f(w.w); lW[c8 + 7][ol] = bf2f(w.w >> 16);
      }
    }
    __syncthreads();
#pragma unroll
    for (int c = 0; c < 32; c++) {
      float4 xa = *(const float4*)&lX[c][tx * 4];
      float4 xb = *(const float4*)&lX[c][64 + tx * 4];
      float4 wa = *(const float4*)&lW[c][ty * 4];
      float4 wb = *(const float4*)&lW[c][64 + ty * 4];
      float xv[8] = {xa.x, xa.y, xa.z, xa.w, xb.x, xb.y, xb.z, xb.w};
      float wv[8] = {wa.x, wa.y, wa.z, wa.w, wb.x, wb.y, wb.z, wb.w};
#pragma unroll
      for (int i = 0; i < 8; i++)
#pragma unroll
        for (int j = 0; j < 8; j++)
          acc[i][j] = fmaf(wv[i], xv[j], acc[i][j]);
    }
  }

#pragma unroll
  for (int i = 0; i < 8; i++) {
    int o = o0 + (i >> 2) * 64 + ty * 4 + (i & 3);
    u16* ob = &out[((size_t)b * QKV + o) * P + p0];
    ushort4 s0, s1;
    s0.x = f2bf(acc[i][0]); s0.y = f2bf(acc[i][1]);
    s0.z = f2bf(acc[i][2]); s0.w = f2bf(acc[i][3]);
    s1.x = f2bf(acc[i][4]); s1.y = f2bf(acc[i][5]);
    s1.z = f2bf(acc[i][6]); s1.w = f2bf(acc[i][7]);
    *(ushort4*)&ob[tx * 4] = s0;
    *(ushort4*)&ob[64 + tx * 4] = s1;
  }
}

// ---- proj GEMM + bias + residual (vector ALU, unchanged) ----
__global__ __launch_bounds__(256) void k_proj(
    const u16* __restrict__ A, const u16* __restrict__ W,
    const u16* __restrict__ bias, const u16* __restrict__ res,
    void* __restrict__ outv, size_t out_off, const int* __restrict__ flags,
    int P, int OT) {
  __shared__ float lX[32][132];
  __shared__ float lW[32][132];
  const int t = threadIdx.x;
  const int tx = t & 15, ty = t >> 4;
  const int p0 = blockIdx.x * 128, o0 = blockIdx.y * 128, b = blockIdx.z;

  float acc[8][8];
#pragma unroll
  for (int i = 0; i < 8; i++) {
    float bv = bf2f(bias[o0 + (i >> 2) * 64 + ty * 4 + (i & 3)]);
#pragma unroll
    for (int j = 0; j < 8; j++) acc[i][j] = bv;
  }

  for (int c0 = 0; c0 < DIM; c0 += 32) {
    __syncthreads();
#pragma unroll
    for (int chh = 0; chh < 2; chh++) {
      int chunk = t + chh * 256;
      {
        int cl = chunk >> 4, el = (chunk & 15) * 8;
        uint4 u = *(const uint4*)&A[((size_t)b * QKV + c0 + cl) * P + p0 + el];
        float* dx = &lX[cl][el];
        dx[0] = bf2f(u.x); dx[1] = bf2f(u.x >> 16);
        dx[2] = bf2f(u.y); dx[3] = bf2f(u.y >> 16);
        dx[4] = bf2f(u.z); dx[5] = bf2f(u.z >> 16);
        dx[6] = bf2f(u.w); dx[7] = bf2f(u.w >> 16);
      }
      {
        int ol = chunk >> 2, c8 = (chunk & 3) * 8;
        uint4 w = *(const uint4*)&W[(size_t)(o0 + ol) * DIM + c0 + c8];
        lW[c8 + 0][ol] = bf2f(w.x); lW[c8 + 1][ol] = bf2f(w.x >> 16);
        lW[c8 + 2][ol] = bf2f(w.y); lW[c8 + 3][ol] = bf2f(w.y >> 16);
        lW[c8 + 4][ol] = bf2f(w.z); lW[c8 + 5][ol] = bf2f(w.z >> 16);
        lW[c8 + 6][ol] = bf2f(w.w); lW[c8 + 7][ol] = bf2f(w.w >> 16);
      }
    }
    __syncthreads();
#pragma unroll
    for (int c = 0; c < 32; c++) {
      float4 xa = *(const float4*)&lX[c][tx * 4];
      float4 xb = *(const float4*)&lX[c][64 + tx * 4];
      float4 wa = *(const float4*)&lW[c][ty * 4];
      float4 wb = *(const float4*)&lW[c][64 + ty * 4];
      float xv[8] = {xa.x, xa.y, xa.z, xa.w, xb.x, xb.y, xb.z, xb.w};
      float wv[8] = {wa.x, wa.y, wa.z, wa.w, wb.x, wb.y, wb.z, wb.w};
#pragma unroll
      for (int i = 0; i < 8; i++)
#pragma unroll
        for (int j = 0; j < 8; j++)
          acc[i][j] = fmaf(wv[i], xv[j], acc[i][j]);
    }
  }

  const bool f32out = (flags[0] != 0);
#pragma unroll
  for (int i = 0; i < 8; i++) {
    int o = o0 + (i >> 2) * 64 + ty * 4 + (i & 3);
    size_t base = ((size_t)b * OT + o) * P + p0;
#pragma unroll
    for (int part = 0; part < 2; part++) {
      int p = part * 64 + tx * 4;
      ushort4 r = *(const ushort4*)&res[base + p];
      float v0 = acc[i][part * 4 + 0] + bf2f(r.x);
      float v1 = acc[i][part * 4 + 1] + bf2f(r.y);
      float v2 = acc[i][part * 4 + 2] + bf2f(r.z);
      float v3 = acc[i][part * 4 + 3] + bf2f(r.w);
      if (f32out) {
        float* of = (float*)outv + out_off;
        *(float4*)&of[base + p] = make_float4(v0, v1, v2, v3);
      } else {
        u16* ob = (u16*)outv + out_off;
        ushort4 w;
        w.x = f2bf(v0); w.y = f2bf(v1); w.z = f2bf(v2); w.w = f2bf(v3);
        *(ushort4*)&ob[base + p] = w;
      }
    }
  }
}

// ---- MFMA flash attention: one 64-thread wave per 16-query tile ----
// S^T[32k][16q] per chunk via 2x mfma_f32_16x16x32_bf16 (A=K[key][d] strided
// u16 loads; B=Q[d][q] direct channel-major, loaded once, pre-scaled GAMMA).
// Online softmax: each lane owns ONE q and 8 keys -> reg-tree + shfl 16/32.
// P^T -> LDS (C->B layout round trip) -> PV with A=V' channel-major direct
// (one dwordx4 per d-tile). O^T accum in regs; epilogue stores channel-major
// into the aliased q-region of qkvq.
__global__ __launch_bounds__(64) void k_attn2(
    u16* __restrict__ qkvq, const u16* __restrict__ qkvkv, int Pq, int Pk) {
  __shared__ u16 Pld[32 * 17];
  const int lane = threadIdx.x;        // 0..63
  const int ql = lane & 15, quad = lane >> 4;
  const int q0 = blockIdx.x * 16;
  const int h = blockIdx.y, b = blockIdx.z;
  u16* qb = qkvq + ((size_t)b * QKV + h * HD) * Pq;
  const u16* kb = qkvkv + ((size_t)b * QKV + DIM + h * HD) * Pk;
  const u16* vb = qkvkv + ((size_t)b * QKV + 2 * DIM + h * HD) * Pk;

  // Q fragment (B-operand): B[d][q], d = quad*8+j, q = q0+ql. Pre-scale GAMMA.
  short8 qf;
#pragma unroll
  for (int j = 0; j < 8; j++) {
    float v = bf2f(qb[(size_t)(quad * 8 + j) * Pq + q0 + ql]) * GAMMA;
    qf[j] = (short)f2bf(v);
  }

  f32x4 o0 = {0.f, 0.f, 0.f, 0.f};
  f32x4 o1 = {0.f, 0.f, 0.f, 0.f};
  float m_run = -1e30f, l_run = 0.f;

  for (int k0 = 0; k0 < Pk; k0 += 32) {
    // K fragments (A-operand): A[key][d] from K'[d][key] (strided u16)
    short8 kf0, kf1;
    const u16* kc0 = kb + k0 + ql;
#pragma unroll
    for (int j = 0; j < 8; j++) {
      size_t row = (size_t)(quad * 8 + j) * Pk;
      kf0[j] = (short)kc0[row];
      kf1[j] = (short)kc0[row + 16];
    }
    // V fragments (A-operand for PV): A[d][key] from V' rows (16B vector)
    union { uint4 u; short8 s; } vv0, vv1;
    vv0.u = *(const uint4*)&vb[(size_t)ql * Pk + k0 + quad * 8];
    vv1.u = *(const uint4*)&vb[(size_t)(16 + ql) * Pk + k0 + quad * 8];

    f32x4 z = {0.f, 0.f, 0.f, 0.f};
    f32x4 st0 = __builtin_amdgcn_mfma_f32_16x16x32_bf16(kf0, qf, z, 0, 0, 0);
    f32x4 st1 = __builtin_amdgcn_mfma_f32_16x16x32_bf16(kf1, qf, z, 0, 0, 0);

    // online softmax: lane owns q = q0+ql, keys k0 + {quad*4+r, 16+quad*4+r}
    float s[8] = {st0[0], st0[1], st0[2], st0[3], st1[0], st1[1], st1[2], st1[3]};
    float cm = fmaxf(fmaxf(fmaxf(s[0], s[1]), fmaxf(s[2], s[3])),
                     fmaxf(fmaxf(s[4], s[5]), fmaxf(s[6], s[7])));
    cm = fmaxf(cm, __shfl_xor(cm, 16));
    cm = fmaxf(cm, __shfl_xor(cm, 32));
    float m_new = fmaxf(m_run, cm);
    float alpha = __expf(m_run - m_new);
    float p[8], ls = 0.f;
#pragma unroll
    for (int i = 0; i < 8; i++) { p[i] = __expf(s[i] - m_new); ls += p[i]; }
    ls += __shfl_xor(ls, 16);
    ls += __shfl_xor(ls, 32);
    l_run = l_run * alpha + ls;
    m_run = m_new;
#pragma unroll
    for (int r = 0; r < 4; r++) { o0[r] *= alpha; o1[r] *= alpha; }

    // P^T round trip: write C-layout (row k = t*16+quad*4+r, col q = ql)
#pragma unroll
    for (int t = 0; t < 2; t++)
#pragma unroll
      for (int r = 0; r < 4; r++)
        Pld[(t * 16 + quad * 4 + r) * 17 + ql] = f2bf(p[t * 4 + r]);
    __syncthreads();
    // read B-layout: B[k][q], k = quad*8+j
    short8 pf;
#pragma unroll
    for (int j = 0; j < 8; j++) pf[j] = (short)Pld[(quad * 8 + j) * 17 + ql];

    o0 = __builtin_amdgcn_mfma_f32_16x16x32_bf16(vv0.s, pf, o0, 0, 0, 0);
    o1 = __builtin_amdgcn_mfma_f32_16x16x32_bf16(vv1.s, pf, o1, 0, 0, 0);
    __syncthreads();  // Pld reuse next chunk
  }

  // O^T store: lane (col q=ql, rows d = t*16 + quad*4 + r) -> channel-major
  float inv = 1.0f / l_run;
#pragma unroll
  for (int r = 0; r < 4; r++) {
    qb[(size_t)(quad * 4 + r) * Pq + q0 + ql] = f2bf(o0[r] * inv);
    qb[(size_t)(16 + quad * 4 + r) * Pq + q0 + ql] = f2bf(o1[r] * inv);
  }
}

extern "C" void kernel_launch(void* const* d_in, const int* in_sizes, int n_in,
                              void* d_out, int out_size, void* d_ws, size_t ws_size,
                              hipStream_t stream) {
  (void)in_sizes; (void)n_in; (void)out_size; (void)ws_size;
  u16* ws = (u16*)d_ws;
  int* flags = (int*)(ws + OFF_FLAGS);
  u16* cx   = ws + OFF_CXB;
  u16* cy   = ws + OFF_CYB;
  u16* cwx  = ws + OFF_CWX;
  u16* cbx  = ws + OFF_CBX;
  u16* cwy  = ws + OFF_CWY;
  u16* cby  = ws + OFF_CBY;
  u16* cwpx = ws + OFF_CWPX;
  u16* cbpx = ws + OFF_CBPX;
  u16* cwpy = ws + OFF_CWPY;
  u16* cbpy = ws + OFF_CBPY;
  u16* qkvx = ws + OFF_QKVX;
  u16* qkvy = ws + OFF_QKVY;

  // 0. detect per-tensor dtype, normalize to bf16 copies in ws
  k_detect<<<dim3(10), 256, 0, stream>>>(
      (const u16*)d_in[0], (const u16*)d_in[1], (const u16*)d_in[2], (const u16*)d_in[3],
      (const u16*)d_in[4], (const u16*)d_in[5], (const u16*)d_in[6], (const u16*)d_in[7],
      (const u16*)d_in[8], (const u16*)d_in[9], flags);
  k_convert<<<dim3(1024, 10), 256, 0, stream>>>(
      d_in[0], d_in[1], d_in[2], d_in[3], d_in[4], d_in[5], d_in[6], d_in[7],
      d_in[8], d_in[9], ws, flags);

  // 1. qkv GEMMs (bf16 out, channel-major)
  k_qkv<<<dim3(PX / 128, 3, B), 256, 0, stream>>>(cx, cwx, cbx, qkvx, CX, PX);
  k_qkv<<<dim3(PY / 128, 3, B), 256, 0, stream>>>(cy, cwy, cby, qkvy, CY, PY);
  // 2. MFMA flash attention; output aliases q-channel region
  k_attn2<<<dim3(PX / 16, NH, B), 64, 0, stream>>>(qkvx, qkvy, PX, PY);
  k_attn2<<<dim3(PY / 16, NH, B), 64, 0, stream>>>(qkvy, qkvx, PY, PX);
  // 3. proj + bias + residual -> out (dtype per flags[0])
  k_proj<<<dim3(PX / 128, CX / 128, B), 256, 0, stream>>>(
      qkvx, cwpx, cbpx, cx, d_out, 0, flags, PX, CX);
  k_proj<<<dim3(PY / 128, CY / 128, B), 256, 0, stream>>>(
      qkvy, cwpy, cbpy, cy, d_out, (size_t)B * CX * PX, flags, PY, CY);
}

// Round 5
// 306.707 us; speedup vs baseline: 2.3870x; 1.1308x over previous
//
#include <hip/hip_runtime.h>
#include <hip/hip_bf16.h>
#include <cstdint>

#define B 2
#define NH 4
#define HD 32
#define DIM 128
#define CX 256
#define CY 512
#define PX 4096
#define PY 1024
#define QKV 384
#define GAMMA 0.17677669529663687f

typedef unsigned short u16;
typedef unsigned int u32;

using short8 = __attribute__((ext_vector_type(8))) short;
using f32x4  = __attribute__((ext_vector_type(4))) float;

__device__ __forceinline__ float bf2f(u32 h) {
  union { u32 u; float f; } v; v.u = (h & 0xffffu) << 16; return v.f;
}
__device__ __forceinline__ u16 f2bf(float f) {
  u32 u = __float_as_uint(f);
  u32 r = (u + 0x7fffu + ((u >> 16) & 1u)) >> 16;
  return (u16)r;
}

// input element counts (compile-time)
#define N_X   (B * CX * PX)
#define N_Y   (B * CY * PY)
#define N_WX  (QKV * CX)
#define N_BX  (QKV)
#define N_WY  (QKV * CY)
#define N_BY  (QKV)
#define N_WPX (CX * DIM)
#define N_BPX (CX)
#define N_WPY (CY * DIM)
#define N_BPY (CY)

// ---- workspace layout (u16 element offsets) ----
enum : size_t {
  OFF_FLAGS = 0,
  OFF_CXB   = 32,
  OFF_CYB   = OFF_CXB  + N_X,
  OFF_CWX   = OFF_CYB  + N_Y,
  OFF_CBX   = OFF_CWX  + N_WX,
  OFF_CWY   = OFF_CBX  + N_BX,
  OFF_CBY   = OFF_CWY  + N_WY,
  OFF_CWPX  = OFF_CBY  + N_BY,
  OFF_CBPX  = OFF_CWPX + N_WPX,
  OFF_CWPY  = OFF_CBPX + N_BPX,
  OFF_CBPY  = OFF_CWPY + N_WPY,
  OFF_QKVX  = OFF_CBPY + N_BPY,
  OFF_QKVY  = OFF_QKVX + (size_t)B * QKV * PX,
  OFF_KTX   = OFF_QKVY + (size_t)B * QKV * PY,   // [B][NH][PX][HD] token-major K of x
  OFF_KTY   = OFF_KTX  + (size_t)B * NH * PX * HD, // [B][NH][PY][HD]
  WS_END    = OFF_KTY  + (size_t)B * NH * PY * HD, // ~17.8 MB
};

// ---- per-tensor dtype detection (bf16 vs f32) ----
__global__ void k_detect(const u16* x, const u16* y, const u16* wx, const u16* bx,
                         const u16* wy, const u16* by, const u16* wpx, const u16* bpx,
                         const u16* wpy, const u16* bpy, int* flags) {
  const u16* p; int n;
  switch (blockIdx.x) {
    case 0: p = x;   n = N_X;   break;
    case 1: p = y;   n = N_Y;   break;
    case 2: p = wx;  n = N_WX;  break;
    case 3: p = bx;  n = N_BX;  break;
    case 4: p = wy;  n = N_WY;  break;
    case 5: p = by;  n = N_BY;  break;
    case 6: p = wpx; n = N_WPX; break;
    case 7: p = bpx; n = N_BPX; break;
    case 8: p = wpy; n = N_WPY; break;
    default: p = bpy; n = N_BPY; break;
  }
  int ncheck = n / 2; if (ncheck > 4096) ncheck = 4096;
  int cnt = 0;
  for (int i = threadIdx.x; i < ncheck; i += 256) {
    u32 u = p[2 * i];
    if ((u & 0x7F80u) >= 0x4600u) cnt++;
  }
  __shared__ int red[256];
  red[threadIdx.x] = cnt;
  __syncthreads();
  for (int s = 128; s > 0; s >>= 1) {
    if ((int)threadIdx.x < s) red[threadIdx.x] += red[threadIdx.x + s];
    __syncthreads();
  }
  if (threadIdx.x == 0) flags[blockIdx.x] = (red[0] * 4 >= ncheck) ? 1 : 0;
}

// ---- normalize every input to a bf16 copy in ws ----
__global__ void k_convert(const void* x, const void* y, const void* wx, const void* bx,
                          const void* wy, const void* by, const void* wpx, const void* bpx,
                          const void* wpy, const void* bpy,
                          u16* __restrict__ ws, const int* __restrict__ flags) {
  const void* src; size_t dstoff; int n;
  switch (blockIdx.y) {
    case 0: src = x;   dstoff = OFF_CXB;  n = N_X;   break;
    case 1: src = y;   dstoff = OFF_CYB;  n = N_Y;   break;
    case 2: src = wx;  dstoff = OFF_CWX;  n = N_WX;  break;
    case 3: src = bx;  dstoff = OFF_CBX;  n = N_BX;  break;
    case 4: src = wy;  dstoff = OFF_CWY;  n = N_WY;  break;
    case 5: src = by;  dstoff = OFF_CBY;  n = N_BY;  break;
    case 6: src = wpx; dstoff = OFF_CWPX; n = N_WPX; break;
    case 7: src = bpx; dstoff = OFF_CBPX; n = N_BPX; break;
    case 8: src = wpy; dstoff = OFF_CWPY; n = N_WPY; break;
    default: src = bpy; dstoff = OFF_CBPY; n = N_BPY; break;
  }
  int e0 = (blockIdx.x * 256 + threadIdx.x) * 8;
  if (e0 >= n) return;
  u16* dst = ws + dstoff + e0;
  if (flags[blockIdx.y]) {
    const float* s = (const float*)src + e0;
    float4 a = *(const float4*)s;
    float4 bq = *(const float4*)(s + 4);
    ushort4 o0, o1;
    o0.x = f2bf(a.x);  o0.y = f2bf(a.y);  o0.z = f2bf(a.z);  o0.w = f2bf(a.w);
    o1.x = f2bf(bq.x); o1.y = f2bf(bq.y); o1.z = f2bf(bq.z); o1.w = f2bf(bq.w);
    *(ushort4*)dst = o0;
    *(ushort4*)(dst + 4) = o1;
  } else {
    uint4 v = *(const uint4*)((const u16*)src + e0);
    *(uint4*)dst = v;
  }
}

// ---- qkv GEMM (vector ALU, unchanged from passing R3/R4) ----
__global__ __launch_bounds__(256) void k_qkv(
    const u16* __restrict__ X, const u16* __restrict__ W,
    const u16* __restrict__ bias, u16* __restrict__ out,
    int C, int P) {
  __shared__ float lX[32][132];
  __shared__ float lW[32][132];
  const int t = threadIdx.x;
  const int tx = t & 15, ty = t >> 4;
  const int p0 = blockIdx.x * 128, o0 = blockIdx.y * 128, b = blockIdx.z;

  float acc[8][8];
#pragma unroll
  for (int i = 0; i < 8; i++) {
    float bv = bf2f(bias[o0 + (i >> 2) * 64 + ty * 4 + (i & 3)]);
#pragma unroll
    for (int j = 0; j < 8; j++) acc[i][j] = bv;
  }

  for (int c0 = 0; c0 < C; c0 += 32) {
    __syncthreads();
#pragma unroll
    for (int chh = 0; chh < 2; chh++) {
      int chunk = t + chh * 256;
      {
        int cl = chunk >> 4, el = (chunk & 15) * 8;
        uint4 u = *(const uint4*)&X[((size_t)b * C + c0 + cl) * P + p0 + el];
        float* dx = &lX[cl][el];
        dx[0] = bf2f(u.x); dx[1] = bf2f(u.x >> 16);
        dx[2] = bf2f(u.y); dx[3] = bf2f(u.y >> 16);
        dx[4] = bf2f(u.z); dx[5] = bf2f(u.z >> 16);
        dx[6] = bf2f(u.w); dx[7] = bf2f(u.w >> 16);
      }
      {
        int ol = chunk >> 2, c8 = (chunk & 3) * 8;
        uint4 w = *(const uint4*)&W[(size_t)(o0 + ol) * C + c0 + c8];
        lW[c8 + 0][ol] = bf2f(w.x); lW[c8 + 1][ol] = bf2f(w.x >> 16);
        lW[c8 + 2][ol] = bf2f(w.y); lW[c8 + 3][ol] = bf2f(w.y >> 16);
        lW[c8 + 4][ol] = bf2f(w.z); lW[c8 + 5][ol] = bf2f(w.z >> 16);
        lW[c8 + 6][ol] = bf2f(w.w); lW[c8 + 7][ol] = bf2f(w.w >> 16);
      }
    }
    __syncthreads();
#pragma unroll
    for (int c = 0; c < 32; c++) {
      float4 xa = *(const float4*)&lX[c][tx * 4];
      float4 xb = *(const float4*)&lX[c][64 + tx * 4];
      float4 wa = *(const float4*)&lW[c][ty * 4];
      float4 wb = *(const float4*)&lW[c][64 + ty * 4];
      float xv[8] = {xa.x, xa.y, xa.z, xa.w, xb.x, xb.y, xb.z, xb.w};
      float wv[8] = {wa.x, wa.y, wa.z, wa.w, wb.x, wb.y, wb.z, wb.w};
#pragma unroll
      for (int i = 0; i < 8; i++)
#pragma unroll
        for (int j = 0; j < 8; j++)
          acc[i][j] = fmaf(wv[i], xv[j], acc[i][j]);
    }
  }

#pragma unroll
  for (int i = 0; i < 8; i++) {
    int o = o0 + (i >> 2) * 64 + ty * 4 + (i & 3);
    u16* ob = &out[((size_t)b * QKV + o) * P + p0];
    ushort4 s0, s1;
    s0.x = f2bf(acc[i][0]); s0.y = f2bf(acc[i][1]);
    s0.z = f2bf(acc[i][2]); s0.w = f2bf(acc[i][3]);
    s1.x = f2bf(acc[i][4]); s1.y = f2bf(acc[i][5]);
    s1.z = f2bf(acc[i][6]); s1.w = f2bf(acc[i][7]);
    *(ushort4*)&ob[tx * 4] = s0;
    *(ushort4*)&ob[64 + tx * 4] = s1;
  }
}

// ---- K transpose: channel-major K region of qkv -> token-major kt ----
// grid (P/32, NH, B), block 256 (= 32 x 8). 32x32 LDS tile.
__global__ __launch_bounds__(256) void k_ktrans(
    const u16* __restrict__ qkv, u16* __restrict__ kt, int P) {
  __shared__ u16 tile[32][33];
  const int tx = threadIdx.x & 31, ty = threadIdx.x >> 5;  // ty 0..7
  const int p0 = blockIdx.x * 32, h = blockIdx.y, b = blockIdx.z;
  const u16* src = qkv + ((size_t)b * QKV + DIM + h * HD) * P;
#pragma unroll
  for (int i = 0; i < 4; i++) {
    int d = ty * 4 + i;
    tile[d][tx] = src[(size_t)d * P + p0 + tx];
  }
  __syncthreads();
  u16* dst = kt + (size_t)(b * NH + h) * P * HD;
#pragma unroll
  for (int i = 0; i < 4; i++) {
    int r = ty * 4 + i;
    dst[(size_t)(p0 + r) * HD + tx] = tile[tx][r];
  }
}

// ---- proj GEMM + bias + residual (vector ALU, unchanged) ----
__global__ __launch_bounds__(256) void k_proj(
    const u16* __restrict__ A, const u16* __restrict__ W,
    const u16* __restrict__ bias, const u16* __restrict__ res,
    void* __restrict__ outv, size_t out_off, const int* __restrict__ flags,
    int P, int OT) {
  __shared__ float lX[32][132];
  __shared__ float lW[32][132];
  const int t = threadIdx.x;
  const int tx = t & 15, ty = t >> 4;
  const int p0 = blockIdx.x * 128, o0 = blockIdx.y * 128, b = blockIdx.z;

  float acc[8][8];
#pragma unroll
  for (int i = 0; i < 8; i++) {
    float bv = bf2f(bias[o0 + (i >> 2) * 64 + ty * 4 + (i & 3)]);
#pragma unroll
    for (int j = 0; j < 8; j++) acc[i][j] = bv;
  }

  for (int c0 = 0; c0 < DIM; c0 += 32) {
    __syncthreads();
#pragma unroll
    for (int chh = 0; chh < 2; chh++) {
      int chunk = t + chh * 256;
      {
        int cl = chunk >> 4, el = (chunk & 15) * 8;
        uint4 u = *(const uint4*)&A[((size_t)b * QKV + c0 + cl) * P + p0 + el];
        float* dx = &lX[cl][el];
        dx[0] = bf2f(u.x); dx[1] = bf2f(u.x >> 16);
        dx[2] = bf2f(u.y); dx[3] = bf2f(u.y >> 16);
        dx[4] = bf2f(u.z); dx[5] = bf2f(u.z >> 16);
        dx[6] = bf2f(u.w); dx[7] = bf2f(u.w >> 16);
      }
      {
        int ol = chunk >> 2, c8 = (chunk & 3) * 8;
        uint4 w = *(const uint4*)&W[(size_t)(o0 + ol) * DIM + c0 + c8];
        lW[c8 + 0][ol] = bf2f(w.x); lW[c8 + 1][ol] = bf2f(w.x >> 16);
        lW[c8 + 2][ol] = bf2f(w.y); lW[c8 + 3][ol] = bf2f(w.y >> 16);
        lW[c8 + 4][ol] = bf2f(w.z); lW[c8 + 5][ol] = bf2f(w.z >> 16);
        lW[c8 + 6][ol] = bf2f(w.w); lW[c8 + 7][ol] = bf2f(w.w >> 16);
      }
    }
    __syncthreads();
#pragma unroll
    for (int c = 0; c < 32; c++) {
      float4 xa = *(const float4*)&lX[c][tx * 4];
      float4 xb = *(const float4*)&lX[c][64 + tx * 4];
      float4 wa = *(const float4*)&lW[c][ty * 4];
      float4 wb = *(const float4*)&lW[c][64 + ty * 4];
      float xv[8] = {xa.x, xa.y, xa.z, xa.w, xb.x, xb.y, xb.z, xb.w};
      float wv[8] = {wa.x, wa.y, wa.z, wa.w, wb.x, wb.y, wb.z, wb.w};
#pragma unroll
      for (int i = 0; i < 8; i++)
#pragma unroll
        for (int j = 0; j < 8; j++)
          acc[i][j] = fmaf(wv[i], xv[j], acc[i][j]);
    }
  }

  const bool f32out = (flags[0] != 0);
#pragma unroll
  for (int i = 0; i < 8; i++) {
    int o = o0 + (i >> 2) * 64 + ty * 4 + (i & 3);
    size_t base = ((size_t)b * OT + o) * P + p0;
#pragma unroll
    for (int part = 0; part < 2; part++) {
      int p = part * 64 + tx * 4;
      ushort4 r = *(const ushort4*)&res[base + p];
      float v0 = acc[i][part * 4 + 0] + bf2f(r.x);
      float v1 = acc[i][part * 4 + 1] + bf2f(r.y);
      float v2 = acc[i][part * 4 + 2] + bf2f(r.z);
      float v3 = acc[i][part * 4 + 3] + bf2f(r.w);
      if (f32out) {
        float* of = (float*)outv + out_off;
        *(float4*)&of[base + p] = make_float4(v0, v1, v2, v3);
      } else {
        u16* ob = (u16*)outv + out_off;
        ushort4 w;
        w.x = f2bf(v0); w.y = f2bf(v1); w.z = f2bf(v2); w.w = f2bf(v3);
        *(ushort4*)&ob[base + p] = w;
      }
    }
  }
}

// ---- MFMA flash attention v3: wave per 16-q tile, 64-key chunks,
//      vector K loads (token-major), register double-buffered K/V ----
__global__ __launch_bounds__(64) void k_attn3(
    u16* __restrict__ qkvq, const u16* __restrict__ qkvkv,
    const u16* __restrict__ kt, int Pq, int Pk) {
  __shared__ u16 Pld[16][72];   // rows 144 B (16B-aligned); packed uint2 writes
  const int lane = threadIdx.x;
  const int ql = lane & 15, quad = lane >> 4;
  const int q0 = blockIdx.x * 16;
  const int h = blockIdx.y, b = blockIdx.z;
  u16* qb = qkvq + ((size_t)b * QKV + h * HD) * Pq;
  const u16* vb = qkvkv + ((size_t)b * QKV + 2 * DIM + h * HD) * Pk;
  const u16* ktb = kt + (size_t)(b * NH + h) * Pk * HD;

  // Q fragment (B-operand): B[d=quad*8+j][q=ql], pre-scaled by GAMMA (once)
  short8 qf;
#pragma unroll
  for (int j = 0; j < 8; j++) {
    float v = bf2f(qb[(size_t)(quad * 8 + j) * Pq + q0 + ql]) * GAMMA;
    qf[j] = (short)f2bf(v);
  }

  f32x4 o0 = {0.f, 0.f, 0.f, 0.f};
  f32x4 o1 = {0.f, 0.f, 0.f, 0.f};
  float m_run = -1e30f, l_run = 0.f;

  union U { uint4 u; short8 s; };
  U kc[4], vc[4], kn[4], vn[4];
  // K frag t: A[key=t*16+ql][d=quad*8+j] -> one dwordx4 (token-major)
#pragma unroll
  for (int t = 0; t < 4; t++)
    kc[t].u = *(const uint4*)&ktb[(size_t)(t * 16 + ql) * HD + quad * 8];
  // V frag (ot,ks): A[d=ot*16+ql][key=ks*32+quad*8+j] -> dwordx4 (chan-major)
#pragma unroll
  for (int ot = 0; ot < 2; ot++)
#pragma unroll
    for (int ks = 0; ks < 2; ks++)
      vc[ot * 2 + ks].u = *(const uint4*)&vb[(size_t)(ot * 16 + ql) * Pk + ks * 32 + quad * 8];

  for (int k0 = 0; k0 < Pk; k0 += 64) {
    // prefetch next chunk (wraps to 0 on last iter; loaded but unused)
    int nk0 = (k0 + 64 < Pk) ? k0 + 64 : 0;
#pragma unroll
    for (int t = 0; t < 4; t++)
      kn[t].u = *(const uint4*)&ktb[(size_t)(nk0 + t * 16 + ql) * HD + quad * 8];
#pragma unroll
    for (int ot = 0; ot < 2; ot++)
#pragma unroll
      for (int ks = 0; ks < 2; ks++)
        vn[ot * 2 + ks].u = *(const uint4*)&vb[(size_t)(ot * 16 + ql) * Pk + nk0 + ks * 32 + quad * 8];

    // S^T chunks: 4x MFMA -> lane owns q=ql, keys k0 + t*16 + quad*4 + r
    f32x4 z = {0.f, 0.f, 0.f, 0.f};
    f32x4 st[4];
#pragma unroll
    for (int t = 0; t < 4; t++)
      st[t] = __builtin_amdgcn_mfma_f32_16x16x32_bf16(kc[t].s, qf, z, 0, 0, 0);

    // online softmax over this lane's 16 scores + cross-quad shuffles
    float s[16];
#pragma unroll
    for (int t = 0; t < 4; t++)
#pragma unroll
      for (int r = 0; r < 4; r++) s[t * 4 + r] = st[t][r];
    float cm = s[0];
#pragma unroll
    for (int i = 1; i < 16; i++) cm = fmaxf(cm, s[i]);
    cm = fmaxf(cm, __shfl_xor(cm, 16));
    cm = fmaxf(cm, __shfl_xor(cm, 32));
    float m_new = fmaxf(m_run, cm);
    float alpha = __expf(m_run - m_new);
    float p[16], ls = 0.f;
#pragma unroll
    for (int i = 0; i < 16; i++) { p[i] = __expf(s[i] - m_new); ls += p[i]; }
    ls += __shfl_xor(ls, 16);
    ls += __shfl_xor(ls, 32);
    l_run = l_run * alpha + ls;
    m_run = m_new;
#pragma unroll
    for (int r = 0; r < 4; r++) { o0[r] *= alpha; o1[r] *= alpha; }

    // route P^T: C-layout -> B-layout via LDS. packed 8B stores.
    __syncthreads();
#pragma unroll
    for (int t = 0; t < 4; t++) {
      uint2 pp;
      pp.x = (u32)f2bf(p[t * 4 + 0]) | ((u32)f2bf(p[t * 4 + 1]) << 16);
      pp.y = (u32)f2bf(p[t * 4 + 2]) | ((u32)f2bf(p[t * 4 + 3]) << 16);
      *(uint2*)&Pld[ql][t * 16 + quad * 4] = pp;
    }
    __syncthreads();
    U pf0, pf1;
    pf0.u = *(const uint4*)&Pld[ql][quad * 8];
    pf1.u = *(const uint4*)&Pld[ql][32 + quad * 8];

    // PV: O^T[d][q] accumulate
    o0 = __builtin_amdgcn_mfma_f32_16x16x32_bf16(vc[0].s, pf0.s, o0, 0, 0, 0);
    o0 = __builtin_amdgcn_mfma_f32_16x16x32_bf16(vc[1].s, pf1.s, o0, 0, 0, 0);
    o1 = __builtin_amdgcn_mfma_f32_16x16x32_bf16(vc[2].s, pf0.s, o1, 0, 0, 0);
    o1 = __builtin_amdgcn_mfma_f32_16x16x32_bf16(vc[3].s, pf1.s, o1, 0, 0, 0);

#pragma unroll
    for (int i = 0; i < 4; i++) { kc[i] = kn[i]; vc[i] = vn[i]; }
  }

  // store O^T into aliased q-channel region: rows d, col q
  float inv = 1.0f / l_run;
#pragma unroll
  for (int r = 0; r < 4; r++) {
    qb[(size_t)(quad * 4 + r) * Pq + q0 + ql] = f2bf(o0[r] * inv);
    qb[(size_t)(16 + quad * 4 + r) * Pq + q0 + ql] = f2bf(o1[r] * inv);
  }
}

extern "C" void kernel_launch(void* const* d_in, const int* in_sizes, int n_in,
                              void* d_out, int out_size, void* d_ws, size_t ws_size,
                              hipStream_t stream) {
  (void)in_sizes; (void)n_in; (void)out_size; (void)ws_size;
  u16* ws = (u16*)d_ws;
  int* flags = (int*)(ws + OFF_FLAGS);
  u16* cx   = ws + OFF_CXB;
  u16* cy   = ws + OFF_CYB;
  u16* cwx  = ws + OFF_CWX;
  u16* cbx  = ws + OFF_CBX;
  u16* cwy  = ws + OFF_CWY;
  u16* cby  = ws + OFF_CBY;
  u16* cwpx = ws + OFF_CWPX;
  u16* cbpx = ws + OFF_CBPX;
  u16* cwpy = ws + OFF_CWPY;
  u16* cbpy = ws + OFF_CBPY;
  u16* qkvx = ws + OFF_QKVX;
  u16* qkvy = ws + OFF_QKVY;
  u16* ktx  = ws + OFF_KTX;
  u16* kty  = ws + OFF_KTY;

  // 0. detect per-tensor dtype, normalize to bf16 copies in ws
  k_detect<<<dim3(10), 256, 0, stream>>>(
      (const u16*)d_in[0], (const u16*)d_in[1], (const u16*)d_in[2], (const u16*)d_in[3],
      (const u16*)d_in[4], (const u16*)d_in[5], (const u16*)d_in[6], (const u16*)d_in[7],
      (const u16*)d_in[8], (const u16*)d_in[9], flags);
  k_convert<<<dim3(1024, 10), 256, 0, stream>>>(
      d_in[0], d_in[1], d_in[2], d_in[3], d_in[4], d_in[5], d_in[6], d_in[7],
      d_in[8], d_in[9], ws, flags);

  // 1. qkv GEMMs (bf16 out, channel-major)
  k_qkv<<<dim3(PX / 128, 3, B), 256, 0, stream>>>(cx, cwx, cbx, qkvx, CX, PX);
  k_qkv<<<dim3(PY / 128, 3, B), 256, 0, stream>>>(cy, cwy, cby, qkvy, CY, PY);
  // 1b. K -> token-major
  k_ktrans<<<dim3(PX / 32, NH, B), 256, 0, stream>>>(qkvx, ktx, PX);
  k_ktrans<<<dim3(PY / 32, NH, B), 256, 0, stream>>>(qkvy, kty, PY);
  // 2. MFMA flash attention; output aliases q-channel region
  k_attn3<<<dim3(PX / 16, NH, B), 64, 0, stream>>>(qkvx, qkvy, kty, PX, PY);
  k_attn3<<<dim3(PY / 16, NH, B), 64, 0, stream>>>(qkvy, qkvx, ktx, PY, PX);
  // 3. proj + bias + residual -> out (dtype per flags[0])
  k_proj<<<dim3(PX / 128, CX / 128, B), 256, 0, stream>>>(
      qkvx, cwpx, cbpx, cx, d_out, 0, flags, PX, CX);
  k_proj<<<dim3(PY / 128, CY / 128, B), 256, 0, stream>>>(
      qkvy, cwpy, cbpy, cy, d_out, (size_t)B * CX * PX, flags, PY, CY);
}

// Round 6
// 210.853 us; speedup vs baseline: 3.4722x; 1.4546x over previous
//
#include <hip/hip_runtime.h>
#include <hip/hip_bf16.h>
#include <cstdint>

#define B 2
#define NH 4
#define HD 32
#define DIM 128
#define CX 256
#define CY 512
#define PX 4096
#define PY 1024
#define QKV 384
#define GAMMA 0.17677669529663687f

typedef unsigned short u16;
typedef unsigned int u32;

using short8 = __attribute__((ext_vector_type(8))) short;
using f32x4  = __attribute__((ext_vector_type(4))) float;

__device__ __forceinline__ float bf2f(u32 h) {
  union { u32 u; float f; } v; v.u = (h & 0xffffu) << 16; return v.f;
}
__device__ __forceinline__ u16 f2bf(float f) {
  u32 u = __float_as_uint(f);
  u32 r = (u + 0x7fffu + ((u >> 16) & 1u)) >> 16;
  return (u16)r;
}

#define N_X   (B * CX * PX)
#define N_Y   (B * CY * PY)
#define N_WX  (QKV * CX)
#define N_BX  (QKV)
#define N_WY  (QKV * CY)
#define N_BY  (QKV)
#define N_WPX (CX * DIM)
#define N_BPX (CX)
#define N_WPY (CY * DIM)
#define N_BPY (CY)

// ---- workspace layout (u16 element offsets, all 16B-aligned) ~17.6 MB ----
enum : size_t {
  OFF_FLAGS = 0,                              // 32 u16 = 16 ints
  OFF_CWX   = 32,
  OFF_CBX   = OFF_CWX  + N_WX,
  OFF_CWY   = OFF_CBX  + N_BX,
  OFF_CBY   = OFF_CWY  + N_WY,
  OFF_CWPX  = OFF_CBY  + N_BY,
  OFF_CBPX  = OFF_CWPX + N_WPX,
  OFF_CWPY  = OFF_CBPX + N_BPX,
  OFF_CBPY  = OFF_CWPY + N_WPY,
  OFF_XT    = OFF_CBPY + N_BPY,               // [B][PX][CX] token-major x
  OFF_YT    = OFF_XT   + (size_t)B * PX * CX, // [B][PY][CY]
  OFF_QKTX  = OFF_YT   + (size_t)B * PY * CY, // [B][PX][256] (q:0-127 scaled, k:128-255)
  OFF_QKTY  = OFF_QKTX + (size_t)B * PX * 256,// [B][PY][256]
  OFF_VCX   = OFF_QKTY + (size_t)B * PY * 256,// [B][128][PX] channel-major v
  OFF_VCY   = OFF_VCX  + (size_t)B * DIM * PX,// [B][128][PY]
  OFF_OTX   = OFF_VCY  + (size_t)B * DIM * PY,// [B][PX][128] token-major attn out
  OFF_OTY   = OFF_OTX  + (size_t)B * PX * DIM,// [B][PY][128]
  WS_END    = OFF_OTY  + (size_t)B * PY * DIM,
};

// ---- per-tensor dtype detection (bf16 vs f32) ----
__global__ void k_detect(const u16* x, const u16* y, const u16* wx, const u16* bx,
                         const u16* wy, const u16* by, const u16* wpx, const u16* bpx,
                         const u16* wpy, const u16* bpy, int* flags) {
  const u16* p; int n;
  switch (blockIdx.x) {
    case 0: p = x;   n = N_X;   break;
    case 1: p = y;   n = N_Y;   break;
    case 2: p = wx;  n = N_WX;  break;
    case 3: p = bx;  n = N_BX;  break;
    case 4: p = wy;  n = N_WY;  break;
    case 5: p = by;  n = N_BY;  break;
    case 6: p = wpx; n = N_WPX; break;
    case 7: p = bpx; n = N_BPX; break;
    case 8: p = wpy; n = N_WPY; break;
    default: p = bpy; n = N_BPY; break;
  }
  int ncheck = n / 2; if (ncheck > 4096) ncheck = 4096;
  int cnt = 0;
  for (int i = threadIdx.x; i < ncheck; i += 256) {
    u32 u = p[2 * i];
    if ((u & 0x7F80u) >= 0x4600u) cnt++;
  }
  __shared__ int red[256];
  red[threadIdx.x] = cnt;
  __syncthreads();
  for (int s = 128; s > 0; s >>= 1) {
    if ((int)threadIdx.x < s) red[threadIdx.x] += red[threadIdx.x + s];
    __syncthreads();
  }
  if (threadIdx.x == 0) flags[blockIdx.x] = (red[0] * 4 >= ncheck) ? 1 : 0;
}

// ---- weights/biases -> bf16 copies in ws ----
__global__ void k_convert(const void* wx, const void* bx, const void* wy, const void* by,
                          const void* wpx, const void* bpx, const void* wpy, const void* bpy,
                          u16* __restrict__ ws, const int* __restrict__ flags) {
  const void* src; size_t dstoff; int n;
  switch (blockIdx.y) {
    case 0: src = wx;  dstoff = OFF_CWX;  n = N_WX;  break;
    case 1: src = bx;  dstoff = OFF_CBX;  n = N_BX;  break;
    case 2: src = wy;  dstoff = OFF_CWY;  n = N_WY;  break;
    case 3: src = by;  dstoff = OFF_CBY;  n = N_BY;  break;
    case 4: src = wpx; dstoff = OFF_CWPX; n = N_WPX; break;
    case 5: src = bpx; dstoff = OFF_CBPX; n = N_BPX; break;
    case 6: src = wpy; dstoff = OFF_CWPY; n = N_WPY; break;
    default: src = bpy; dstoff = OFF_CBPY; n = N_BPY; break;
  }
  int e0 = (blockIdx.x * 256 + threadIdx.x) * 8;
  if (e0 >= n) return;
  u16* dst = ws + dstoff + e0;
  if (flags[blockIdx.y + 2]) {
    const float* s = (const float*)src + e0;
    float4 a = *(const float4*)s;
    float4 bq = *(const float4*)(s + 4);
    ushort4 o0, o1;
    o0.x = f2bf(a.x);  o0.y = f2bf(a.y);  o0.z = f2bf(a.z);  o0.w = f2bf(a.w);
    o1.x = f2bf(bq.x); o1.y = f2bf(bq.y); o1.z = f2bf(bq.z); o1.w = f2bf(bq.w);
    *(ushort4*)dst = o0;
    *(ushort4*)(dst + 4) = o1;
  } else {
    uint4 v = *(const uint4*)((const u16*)src + e0);
    *(uint4*)dst = v;
  }
}

// ---- input transpose + convert: src[b][c][p] (dtype per flag) -> dst[b][p][c] bf16 ----
__global__ __launch_bounds__(256) void k_xpose(
    const void* __restrict__ src, u16* __restrict__ dst,
    const int* __restrict__ flags, int fidx, int C, int P) {
  __shared__ u16 tile[32][33];
  const int tx = threadIdx.x & 31, ty = threadIdx.x >> 5;  // ty 0..7
  const int p0 = blockIdx.x * 32, c0 = blockIdx.y * 32, b = blockIdx.z;
  const bool f32in = flags[fidx] != 0;
#pragma unroll
  for (int i = 0; i < 4; i++) {
    int cl = ty * 4 + i;
    size_t sidx = ((size_t)b * C + c0 + cl) * P + p0 + tx;
    u16 v = f32in ? f2bf(((const float*)src)[sidx]) : ((const u16*)src)[sidx];
    tile[cl][tx] = v;
  }
  __syncthreads();
#pragma unroll
  for (int i = 0; i < 4; i++) {
    int pl = ty * 4 + i;
    dst[((size_t)b * P + p0 + pl) * C + c0 + tx] = tile[tx][pl];
  }
}

// ---- unified MFMA GEMM, no LDS: D[o][p] = W[o][:]*Xt[p][:] ----
// block 256 = 4 waves (2o x 2p), block tile 64(o) x 64(p), 32x32 per wave.
// mode 0 (qkv): blockIdx.y<4 -> token-major qk store (scale GAMMA for y<2);
//               blockIdx.y>=4 -> channel-major v store (rows o-256).
// mode 1 (proj): + residual(raw, dtype flag) -> final out (dtype flag).
__global__ __launch_bounds__(256) void k_mm(
    const u16* __restrict__ W, const u16* __restrict__ Xt,
    const u16* __restrict__ bias,
    u16* __restrict__ qkOut, u16* __restrict__ vOut,
    void* __restrict__ pOut, const void* __restrict__ res,
    const int* __restrict__ flags, int fidx, size_t out_off,
    int C, int P, int mode) {
  const int t = threadIdx.x;
  const int lane = t & 63, w = t >> 6;
  const int ql = lane & 15, quad = lane >> 4;
  const int p_w = blockIdx.x * 64 + (w & 1) * 32;
  const int o_w = blockIdx.y * 64 + (w >> 1) * 32;
  const int b = blockIdx.z;

  const u16* wr0 = W + (size_t)(o_w + ql) * C;
  const u16* wr1 = W + (size_t)(o_w + 16 + ql) * C;
  const u16* xr0 = Xt + ((size_t)b * P + p_w + ql) * C;
  const u16* xr1 = Xt + ((size_t)b * P + p_w + 16 + ql) * C;

  union U { uint4 u; short8 s; };
  f32x4 acc[2][2];
#pragma unroll
  for (int i = 0; i < 2; i++)
#pragma unroll
    for (int j = 0; j < 2; j++) acc[i][j] = (f32x4){0.f, 0.f, 0.f, 0.f};

#pragma unroll 4
  for (int c0 = 0; c0 < C; c0 += 32) {
    int off = c0 + quad * 8;
    U a0, a1, b0, b1;
    a0.u = *(const uint4*)&wr0[off];
    a1.u = *(const uint4*)&wr1[off];
    b0.u = *(const uint4*)&xr0[off];
    b1.u = *(const uint4*)&xr1[off];
    acc[0][0] = __builtin_amdgcn_mfma_f32_16x16x32_bf16(a0.s, b0.s, acc[0][0], 0, 0, 0);
    acc[0][1] = __builtin_amdgcn_mfma_f32_16x16x32_bf16(a0.s, b1.s, acc[0][1], 0, 0, 0);
    acc[1][0] = __builtin_amdgcn_mfma_f32_16x16x32_bf16(a1.s, b0.s, acc[1][0], 0, 0, 0);
    acc[1][1] = __builtin_amdgcn_mfma_f32_16x16x32_bf16(a1.s, b1.s, acc[1][1], 0, 0, 0);
  }

  float bs[2][4];
#pragma unroll
  for (int oi = 0; oi < 2; oi++)
#pragma unroll
    for (int r = 0; r < 4; r++)
      bs[oi][r] = bf2f(bias[o_w + oi * 16 + quad * 4 + r]);

  if (mode == 0) {
    if (blockIdx.y < 4) {
      float scale = (blockIdx.y < 2) ? GAMMA : 1.0f;
#pragma unroll
      for (int oi = 0; oi < 2; oi++)
#pragma unroll
        for (int pi = 0; pi < 2; pi++) {
          int p = p_w + pi * 16 + ql;
          int ob = o_w + oi * 16 + quad * 4;
          f32x4 a = acc[oi][pi];
          uint2 pk;
          pk.x = (u32)f2bf((a[0] + bs[oi][0]) * scale) |
                 ((u32)f2bf((a[1] + bs[oi][1]) * scale) << 16);
          pk.y = (u32)f2bf((a[2] + bs[oi][2]) * scale) |
                 ((u32)f2bf((a[3] + bs[oi][3]) * scale) << 16);
          *(uint2*)&qkOut[((size_t)b * P + p) * 256 + ob] = pk;
        }
    } else {
#pragma unroll
      for (int oi = 0; oi < 2; oi++)
#pragma unroll
        for (int pi = 0; pi < 2; pi++) {
          int p = p_w + pi * 16 + ql;
          f32x4 a = acc[oi][pi];
#pragma unroll
          for (int r = 0; r < 4; r++) {
            int o = o_w + oi * 16 + quad * 4 + r - 256;
            vOut[((size_t)b * DIM + o) * P + p] = f2bf(a[r] + bs[oi][r]);
          }
        }
    }
  } else {
    int OT = gridDim.y * 64;
    bool f32io = flags[fidx] != 0;
#pragma unroll
    for (int oi = 0; oi < 2; oi++)
#pragma unroll
      for (int pi = 0; pi < 2; pi++) {
        int p = p_w + pi * 16 + ql;
        f32x4 a = acc[oi][pi];
#pragma unroll
        for (int r = 0; r < 4; r++) {
          int o = o_w + oi * 16 + quad * 4 + r;
          size_t idx = ((size_t)b * OT + o) * P + p;
          float rv = f32io ? ((const float*)res)[idx] : bf2f(((const u16*)res)[idx]);
          float v = a[r] + bs[oi][r] + rv;
          if (f32io) ((float*)pOut)[out_off + idx] = v;
          else       ((u16*)pOut)[out_off + idx] = f2bf(v);
        }
      }
  }
}

// ---- MFMA flash attention v4: all-vector loads, token-major I/O ----
__global__ __launch_bounds__(64) void k_attn4(
    const u16* __restrict__ qkQ, const u16* __restrict__ qkKV,
    const u16* __restrict__ vKV, u16* __restrict__ Ot, int Pq, int Pk) {
  __shared__ u16 Pld[16][72];
  const int lane = threadIdx.x;
  const int ql = lane & 15, quad = lane >> 4;
  const int q0 = blockIdx.x * 16;
  const int h = blockIdx.y, b = blockIdx.z;

  union U { uint4 u; short8 s; };
  // Q (pre-scaled by GAMMA at qkv): B[d=quad*8+j][q=ql], one dwordx4
  U qt; qt.u = *(const uint4*)&qkQ[((size_t)b * Pq + q0 + ql) * 256 + h * HD + quad * 8];
  short8 qf = qt.s;

  const u16* kb = qkKV + (size_t)b * Pk * 256 + 128 + h * HD;   // + row*256
  const u16* vb = vKV + ((size_t)b * DIM + h * HD) * Pk;        // channel-major

  f32x4 o0 = {0.f, 0.f, 0.f, 0.f};
  f32x4 o1 = {0.f, 0.f, 0.f, 0.f};
  float m_run = -1e30f, l_run = 0.f;

  U kc[4], vc[4], kn[4], vn[4];
#pragma unroll
  for (int t = 0; t < 4; t++)
    kc[t].u = *(const uint4*)&kb[(size_t)(t * 16 + ql) * 256 + quad * 8];
#pragma unroll
  for (int ot = 0; ot < 2; ot++)
#pragma unroll
    for (int ks = 0; ks < 2; ks++)
      vc[ot * 2 + ks].u = *(const uint4*)&vb[(size_t)(ot * 16 + ql) * Pk + ks * 32 + quad * 8];

  for (int k0 = 0; k0 < Pk; k0 += 64) {
    int nk0 = (k0 + 64 < Pk) ? k0 + 64 : 0;
#pragma unroll
    for (int t = 0; t < 4; t++)
      kn[t].u = *(const uint4*)&kb[(size_t)(nk0 + t * 16 + ql) * 256 + quad * 8];
#pragma unroll
    for (int ot = 0; ot < 2; ot++)
#pragma unroll
      for (int ks = 0; ks < 2; ks++)
        vn[ot * 2 + ks].u = *(const uint4*)&vb[(size_t)(ot * 16 + ql) * Pk + nk0 + ks * 32 + quad * 8];

    f32x4 z = {0.f, 0.f, 0.f, 0.f};
    f32x4 st[4];
#pragma unroll
    for (int t = 0; t < 4; t++)
      st[t] = __builtin_amdgcn_mfma_f32_16x16x32_bf16(kc[t].s, qf, z, 0, 0, 0);

    float s[16];
#pragma unroll
    for (int t = 0; t < 4; t++)
#pragma unroll
      for (int r = 0; r < 4; r++) s[t * 4 + r] = st[t][r];
    float cm = s[0];
#pragma unroll
    for (int i = 1; i < 16; i++) cm = fmaxf(cm, s[i]);
    cm = fmaxf(cm, __shfl_xor(cm, 16));
    cm = fmaxf(cm, __shfl_xor(cm, 32));
    float m_new = fmaxf(m_run, cm);
    float alpha = __expf(m_run - m_new);
    float p[16], ls = 0.f;
#pragma unroll
    for (int i = 0; i < 16; i++) { p[i] = __expf(s[i] - m_new); ls += p[i]; }
    ls += __shfl_xor(ls, 16);
    ls += __shfl_xor(ls, 32);
    l_run = l_run * alpha + ls;
    m_run = m_new;
#pragma unroll
    for (int r = 0; r < 4; r++) { o0[r] *= alpha; o1[r] *= alpha; }

    __syncthreads();
#pragma unroll
    for (int t = 0; t < 4; t++) {
      uint2 pp;
      pp.x = (u32)f2bf(p[t * 4 + 0]) | ((u32)f2bf(p[t * 4 + 1]) << 16);
      pp.y = (u32)f2bf(p[t * 4 + 2]) | ((u32)f2bf(p[t * 4 + 3]) << 16);
      *(uint2*)&Pld[ql][t * 16 + quad * 4] = pp;
    }
    __syncthreads();
    U pf0, pf1;
    pf0.u = *(const uint4*)&Pld[ql][quad * 8];
    pf1.u = *(const uint4*)&Pld[ql][32 + quad * 8];

    o0 = __builtin_amdgcn_mfma_f32_16x16x32_bf16(vc[0].s, pf0.s, o0, 0, 0, 0);
    o0 = __builtin_amdgcn_mfma_f32_16x16x32_bf16(vc[1].s, pf1.s, o0, 0, 0, 0);
    o1 = __builtin_amdgcn_mfma_f32_16x16x32_bf16(vc[2].s, pf0.s, o1, 0, 0, 0);
    o1 = __builtin_amdgcn_mfma_f32_16x16x32_bf16(vc[3].s, pf1.s, o1, 0, 0, 0);

#pragma unroll
    for (int i = 0; i < 4; i++) { kc[i] = kn[i]; vc[i] = vn[i]; }
  }

  // token-major O store: row q, cols d (packed 4 consecutive d per uint2)
  float inv = 1.0f / l_run;
  u16* ob = Ot + ((size_t)b * Pq + q0 + ql) * DIM + h * HD;
  uint2 s0, s1;
  s0.x = (u32)f2bf(o0[0] * inv) | ((u32)f2bf(o0[1] * inv) << 16);
  s0.y = (u32)f2bf(o0[2] * inv) | ((u32)f2bf(o0[3] * inv) << 16);
  s1.x = (u32)f2bf(o1[0] * inv) | ((u32)f2bf(o1[1] * inv) << 16);
  s1.y = (u32)f2bf(o1[2] * inv) | ((u32)f2bf(o1[3] * inv) << 16);
  *(uint2*)&ob[quad * 4] = s0;
  *(uint2*)&ob[16 + quad * 4] = s1;
}

extern "C" void kernel_launch(void* const* d_in, const int* in_sizes, int n_in,
                              void* d_out, int out_size, void* d_ws, size_t ws_size,
                              hipStream_t stream) {
  (void)in_sizes; (void)n_in; (void)out_size; (void)ws_size;
  u16* ws = (u16*)d_ws;
  int* flags = (int*)(ws + OFF_FLAGS);
  u16* cwx  = ws + OFF_CWX;
  u16* cbx  = ws + OFF_CBX;
  u16* cwy  = ws + OFF_CWY;
  u16* cby  = ws + OFF_CBY;
  u16* cwpx = ws + OFF_CWPX;
  u16* cbpx = ws + OFF_CBPX;
  u16* cwpy = ws + OFF_CWPY;
  u16* cbpy = ws + OFF_CBPY;
  u16* xt   = ws + OFF_XT;
  u16* yt   = ws + OFF_YT;
  u16* qktx = ws + OFF_QKTX;
  u16* qkty = ws + OFF_QKTY;
  u16* vcx  = ws + OFF_VCX;
  u16* vcy  = ws + OFF_VCY;
  u16* otx  = ws + OFF_OTX;
  u16* oty  = ws + OFF_OTY;

  // 0. dtype detect; weight/bias bf16 copies; input transposes (token-major)
  k_detect<<<dim3(10), 256, 0, stream>>>(
      (const u16*)d_in[0], (const u16*)d_in[1], (const u16*)d_in[2], (const u16*)d_in[3],
      (const u16*)d_in[4], (const u16*)d_in[5], (const u16*)d_in[6], (const u16*)d_in[7],
      (const u16*)d_in[8], (const u16*)d_in[9], flags);
  k_convert<<<dim3(96, 8), 256, 0, stream>>>(
      d_in[2], d_in[3], d_in[4], d_in[5], d_in[6], d_in[7], d_in[8], d_in[9], ws, flags);
  k_xpose<<<dim3(PX / 32, CX / 32, B), 256, 0, stream>>>(d_in[0], xt, flags, 0, CX, PX);
  k_xpose<<<dim3(PY / 32, CY / 32, B), 256, 0, stream>>>(d_in[1], yt, flags, 1, CY, PY);

  // 1. qkv GEMMs: q,k -> token-major QKt (q pre-scaled), v -> channel-major Vc
  k_mm<<<dim3(PX / 64, 6, B), 256, 0, stream>>>(
      cwx, xt, cbx, qktx, vcx, nullptr, nullptr, flags, 0, 0, CX, PX, 0);
  k_mm<<<dim3(PY / 64, 6, B), 256, 0, stream>>>(
      cwy, yt, cby, qkty, vcy, nullptr, nullptr, flags, 0, 0, CY, PY, 0);

  // 2. MFMA flash attention -> token-major Ot
  k_attn4<<<dim3(PX / 16, NH, B), 64, 0, stream>>>(qktx, qkty, vcy, otx, PX, PY);
  k_attn4<<<dim3(PY / 16, NH, B), 64, 0, stream>>>(qkty, qktx, vcx, oty, PY, PX);

  // 3. proj + bias + residual -> final out (dtype per flag)
  k_mm<<<dim3(PX / 64, CX / 64, B), 256, 0, stream>>>(
      cwpx, otx, cbpx, nullptr, nullptr, d_out, d_in[0], flags, 0, 0, DIM, PX, 1);
  k_mm<<<dim3(PY / 64, CY / 64, B), 256, 0, stream>>>(
      cwpy, oty, cbpy, nullptr, nullptr, d_out, d_in[1], flags, 1,
      (size_t)B * CX * PX, DIM, PY, 1);
}

// Round 7
// 199.566 us; speedup vs baseline: 3.6686x; 1.0566x over previous
//
#include <hip/hip_runtime.h>
#include <hip/hip_bf16.h>
#include <cstdint>

#define B 2
#define NH 4
#define HD 32
#define DIM 128
#define CX 256
#define CY 512
#define PX 4096
#define PY 1024
#define QKV 384
#define GAMMA 0.17677669529663687f

typedef unsigned short u16;
typedef unsigned int u32;

using short8 = __attribute__((ext_vector_type(8))) short;
using f32x4  = __attribute__((ext_vector_type(4))) float;

__device__ __forceinline__ float bf2f(u32 h) {
  union { u32 u; float f; } v; v.u = (h & 0xffffu) << 16; return v.f;
}
__device__ __forceinline__ u16 f2bf(float f) {
  u32 u = __float_as_uint(f);
  u32 r = (u + 0x7fffu + ((u >> 16) & 1u)) >> 16;
  return (u16)r;
}
__device__ __forceinline__ void gl_lds16(const u16* g, u16* l) {
  __builtin_amdgcn_global_load_lds(
      (const __attribute__((address_space(1))) void*)g,
      (__attribute__((address_space(3))) void*)l, 16, 0, 0);
}

#define N_X   (B * CX * PX)
#define N_Y   (B * CY * PY)
#define N_WX  (QKV * CX)
#define N_BX  (QKV)
#define N_WY  (QKV * CY)
#define N_BY  (QKV)
#define N_WPX (CX * DIM)
#define N_BPX (CX)
#define N_WPY (CY * DIM)
#define N_BPY (CY)

// ---- workspace layout (u16 element offsets, all 16B-aligned) ----
enum : size_t {
  OFF_FLAGS = 0,
  OFF_CWX   = 32,
  OFF_CBX   = OFF_CWX  + N_WX,
  OFF_CWY   = OFF_CBX  + N_BX,
  OFF_CBY   = OFF_CWY  + N_WY,
  OFF_CWPX  = OFF_CBY  + N_BY,
  OFF_CBPX  = OFF_CWPX + N_WPX,
  OFF_CWPY  = OFF_CBPX + N_BPX,
  OFF_CBPY  = OFF_CWPY + N_WPY,
  OFF_XT    = OFF_CBPY + N_BPY,
  OFF_YT    = OFF_XT   + (size_t)B * PX * CX,
  OFF_QKTX  = OFF_YT   + (size_t)B * PY * CY,
  OFF_QKTY  = OFF_QKTX + (size_t)B * PX * 256,
  OFF_VCX   = OFF_QKTY + (size_t)B * PY * 256,
  OFF_VCY   = OFF_VCX  + (size_t)B * DIM * PX,
  OFF_OTX   = OFF_VCY  + (size_t)B * DIM * PY,
  OFF_OTY   = OFF_OTX  + (size_t)B * PX * DIM,
  WS_END    = OFF_OTY  + (size_t)B * PY * DIM,
};

// ---- per-tensor dtype detection (bf16 vs f32) ----
__global__ void k_detect(const u16* x, const u16* y, const u16* wx, const u16* bx,
                         const u16* wy, const u16* by, const u16* wpx, const u16* bpx,
                         const u16* wpy, const u16* bpy, int* flags) {
  const u16* p; int n;
  switch (blockIdx.x) {
    case 0: p = x;   n = N_X;   break;
    case 1: p = y;   n = N_Y;   break;
    case 2: p = wx;  n = N_WX;  break;
    case 3: p = bx;  n = N_BX;  break;
    case 4: p = wy;  n = N_WY;  break;
    case 5: p = by;  n = N_BY;  break;
    case 6: p = wpx; n = N_WPX; break;
    case 7: p = bpx; n = N_BPX; break;
    case 8: p = wpy; n = N_WPY; break;
    default: p = bpy; n = N_BPY; break;
  }
  int ncheck = n / 2; if (ncheck > 4096) ncheck = 4096;
  int cnt = 0;
  for (int i = threadIdx.x; i < ncheck; i += 256) {
    u32 u = p[2 * i];
    if ((u & 0x7F80u) >= 0x4600u) cnt++;
  }
  __shared__ int red[256];
  red[threadIdx.x] = cnt;
  __syncthreads();
  for (int s = 128; s > 0; s >>= 1) {
    if ((int)threadIdx.x < s) red[threadIdx.x] += red[threadIdx.x + s];
    __syncthreads();
  }
  if (threadIdx.x == 0) flags[blockIdx.x] = (red[0] * 4 >= ncheck) ? 1 : 0;
}

// ---- weights/biases -> bf16 copies in ws ----
__global__ void k_convert(const void* wx, const void* bx, const void* wy, const void* by,
                          const void* wpx, const void* bpx, const void* wpy, const void* bpy,
                          u16* __restrict__ ws, const int* __restrict__ flags) {
  const void* src; size_t dstoff; int n;
  switch (blockIdx.y) {
    case 0: src = wx;  dstoff = OFF_CWX;  n = N_WX;  break;
    case 1: src = bx;  dstoff = OFF_CBX;  n = N_BX;  break;
    case 2: src = wy;  dstoff = OFF_CWY;  n = N_WY;  break;
    case 3: src = by;  dstoff = OFF_CBY;  n = N_BY;  break;
    case 4: src = wpx; dstoff = OFF_CWPX; n = N_WPX; break;
    case 5: src = bpx; dstoff = OFF_CBPX; n = N_BPX; break;
    case 6: src = wpy; dstoff = OFF_CWPY; n = N_WPY; break;
    default: src = bpy; dstoff = OFF_CBPY; n = N_BPY; break;
  }
  int e0 = (blockIdx.x * 256 + threadIdx.x) * 8;
  if (e0 >= n) return;
  u16* dst = ws + dstoff + e0;
  if (flags[blockIdx.y + 2]) {
    const float* s = (const float*)src + e0;
    float4 a = *(const float4*)s;
    float4 bq = *(const float4*)(s + 4);
    ushort4 o0, o1;
    o0.x = f2bf(a.x);  o0.y = f2bf(a.y);  o0.z = f2bf(a.z);  o0.w = f2bf(a.w);
    o1.x = f2bf(bq.x); o1.y = f2bf(bq.y); o1.z = f2bf(bq.z); o1.w = f2bf(bq.w);
    *(ushort4*)dst = o0;
    *(ushort4*)(dst + 4) = o1;
  } else {
    uint4 v = *(const uint4*)((const u16*)src + e0);
    *(uint4*)dst = v;
  }
}

// ---- input transpose + convert: src[b][c][p] -> dst[b][p][c] bf16 ----
__global__ __launch_bounds__(256) void k_xpose(
    const void* __restrict__ src, u16* __restrict__ dst,
    const int* __restrict__ flags, int fidx, int C, int P) {
  __shared__ u16 tile[32][33];
  const int tx = threadIdx.x & 31, ty = threadIdx.x >> 5;
  const int p0 = blockIdx.x * 32, c0 = blockIdx.y * 32, b = blockIdx.z;
  const bool f32in = flags[fidx] != 0;
#pragma unroll
  for (int i = 0; i < 4; i++) {
    int cl = ty * 4 + i;
    size_t sidx = ((size_t)b * C + c0 + cl) * P + p0 + tx;
    u16 v = f32in ? f2bf(((const float*)src)[sidx]) : ((const u16*)src)[sidx];
    tile[cl][tx] = v;
  }
  __syncthreads();
#pragma unroll
  for (int i = 0; i < 4; i++) {
    int pl = ty * 4 + i;
    dst[((size_t)b * P + p0 + pl) * C + c0 + tx] = tile[tx][pl];
  }
}

// ---- unified MFMA GEMM (unchanged from passing R6) ----
__global__ __launch_bounds__(256) void k_mm(
    const u16* __restrict__ W, const u16* __restrict__ Xt,
    const u16* __restrict__ bias,
    u16* __restrict__ qkOut, u16* __restrict__ vOut,
    void* __restrict__ pOut, const void* __restrict__ res,
    const int* __restrict__ flags, int fidx, size_t out_off,
    int C, int P, int mode) {
  const int t = threadIdx.x;
  const int lane = t & 63, w = t >> 6;
  const int ql = lane & 15, quad = lane >> 4;
  const int p_w = blockIdx.x * 64 + (w & 1) * 32;
  const int o_w = blockIdx.y * 64 + (w >> 1) * 32;
  const int b = blockIdx.z;

  const u16* wr0 = W + (size_t)(o_w + ql) * C;
  const u16* wr1 = W + (size_t)(o_w + 16 + ql) * C;
  const u16* xr0 = Xt + ((size_t)b * P + p_w + ql) * C;
  const u16* xr1 = Xt + ((size_t)b * P + p_w + 16 + ql) * C;

  union U { uint4 u; short8 s; };
  f32x4 acc[2][2];
#pragma unroll
  for (int i = 0; i < 2; i++)
#pragma unroll
    for (int j = 0; j < 2; j++) acc[i][j] = (f32x4){0.f, 0.f, 0.f, 0.f};

#pragma unroll 4
  for (int c0 = 0; c0 < C; c0 += 32) {
    int off = c0 + quad * 8;
    U a0, a1, b0, b1;
    a0.u = *(const uint4*)&wr0[off];
    a1.u = *(const uint4*)&wr1[off];
    b0.u = *(const uint4*)&xr0[off];
    b1.u = *(const uint4*)&xr1[off];
    acc[0][0] = __builtin_amdgcn_mfma_f32_16x16x32_bf16(a0.s, b0.s, acc[0][0], 0, 0, 0);
    acc[0][1] = __builtin_amdgcn_mfma_f32_16x16x32_bf16(a0.s, b1.s, acc[0][1], 0, 0, 0);
    acc[1][0] = __builtin_amdgcn_mfma_f32_16x16x32_bf16(a1.s, b0.s, acc[1][0], 0, 0, 0);
    acc[1][1] = __builtin_amdgcn_mfma_f32_16x16x32_bf16(a1.s, b1.s, acc[1][1], 0, 0, 0);
  }

  float bs[2][4];
#pragma unroll
  for (int oi = 0; oi < 2; oi++)
#pragma unroll
    for (int r = 0; r < 4; r++)
      bs[oi][r] = bf2f(bias[o_w + oi * 16 + quad * 4 + r]);

  if (mode == 0) {
    if (blockIdx.y < 4) {
      float scale = (blockIdx.y < 2) ? GAMMA : 1.0f;
#pragma unroll
      for (int oi = 0; oi < 2; oi++)
#pragma unroll
        for (int pi = 0; pi < 2; pi++) {
          int p = p_w + pi * 16 + ql;
          int ob = o_w + oi * 16 + quad * 4;
          f32x4 a = acc[oi][pi];
          uint2 pk;
          pk.x = (u32)f2bf((a[0] + bs[oi][0]) * scale) |
                 ((u32)f2bf((a[1] + bs[oi][1]) * scale) << 16);
          pk.y = (u32)f2bf((a[2] + bs[oi][2]) * scale) |
                 ((u32)f2bf((a[3] + bs[oi][3]) * scale) << 16);
          *(uint2*)&qkOut[((size_t)b * P + p) * 256 + ob] = pk;
        }
    } else {
#pragma unroll
      for (int oi = 0; oi < 2; oi++)
#pragma unroll
        for (int pi = 0; pi < 2; pi++) {
          int p = p_w + pi * 16 + ql;
          f32x4 a = acc[oi][pi];
#pragma unroll
          for (int r = 0; r < 4; r++) {
            int o = o_w + oi * 16 + quad * 4 + r - 256;
            vOut[((size_t)b * DIM + o) * P + p] = f2bf(a[r] + bs[oi][r]);
          }
        }
    }
  } else {
    int OT = gridDim.y * 64;
    bool f32io = flags[fidx] != 0;
#pragma unroll
    for (int oi = 0; oi < 2; oi++)
#pragma unroll
      for (int pi = 0; pi < 2; pi++) {
        int p = p_w + pi * 16 + ql;
        f32x4 a = acc[oi][pi];
#pragma unroll
        for (int r = 0; r < 4; r++) {
          int o = o_w + oi * 16 + quad * 4 + r;
          size_t idx = ((size_t)b * OT + o) * P + p;
          float rv = f32io ? ((const float*)res)[idx] : bf2f(((const u16*)res)[idx]);
          float v = a[r] + bs[oi][r] + rv;
          if (f32io) ((float*)pOut)[out_off + idx] = v;
          else       ((u16*)pOut)[out_off + idx] = f2bf(v);
        }
      }
  }
}

// ---- MFMA flash attention v5 ----
// 256-thr blocks = 4 waves, in-block split-K: wave w handles keys
// [w*Pk/4, (w+1)*Pk/4) for the SAME 16 queries; partials merged via LDS.
// K staged to LDS with PERMUTED rows f_t(m) so QK^T's C-layout == PV's
// B-layout (P never leaves the lane; zero barriers in the K-loop).
// Double-buffered global_load_lds paced by per-wave s_waitcnt vmcnt.
__global__ __launch_bounds__(256) void k_attn5(
    const u16* __restrict__ qkQ, const u16* __restrict__ qkKV,
    const u16* __restrict__ vKV, u16* __restrict__ Ot, int Pq, int Pk) {
  __shared__ __align__(16) u16 pool[16384];   // 4 waves x (K dbuf 2x2KB + V dbuf 2x2KB)
  const int t = threadIdx.x;
  const int lane = t & 63, w = t >> 6;
  const int ql = lane & 15, quad = lane >> 4;
  const int q0 = blockIdx.x * 16;
  const int h = blockIdx.y, b = blockIdx.z;

  union U { uint4 u; short8 s; };
  // Q (pre-scaled by GAMMA): B[d=quad*8+j][q=ql]
  U qt; qt.u = *(const uint4*)&qkQ[((size_t)b * Pq + q0 + ql) * 256 + h * HD + quad * 8];

  const int kspan = Pk >> 2;
  const int kk0 = w * kspan;
  const int niter = kspan >> 5;   // 32-key chunks

  // staging source pointers (per lane)
  const u16* gK0 = qkKV + ((size_t)(b * Pk + kk0 + (lane & 31))) * 256 + 128 + h * HD + (lane >> 5) * 8;
  const u16* gK1 = gK0 + 16;                               // d-octet +2
  const u16* gV0 = vKV + ((size_t)(b * DIM + h * HD + (lane & 15))) * Pk + kk0 + (lane >> 4) * 8;
  const u16* gV1 = gV0 + (size_t)16 * Pk;                  // d +16

  u16* wpool = pool + w * 4096;   // per-wave region (u16 units)

  // stage chunk 0 -> buf 0
  gl_lds16(gK0, wpool);
  gl_lds16(gK1, wpool + 512);
  gl_lds16(gV0, wpool + 2048);
  gl_lds16(gV1, wpool + 2048 + 512);

  // K frag LDS offsets (u16): tile t reads key f_t(ql) = (ql>>2)*8 + t*4 + (ql&3)
  const int f0 = ((ql >> 2) << 3) | (ql & 3);
  const int kA0 = (f0 + 32 * quad) * 8;
  const int kA1 = kA0 + 32;               // f+4 keys
  const int vA0 = 2048 + lane * 8;
  const int vA1 = 2048 + 512 + lane * 8;

  f32x4 o0 = {0.f, 0.f, 0.f, 0.f};
  f32x4 o1 = {0.f, 0.f, 0.f, 0.f};
  float m_run = -1e30f, l_run = 0.f;

  int buf = 0;
  for (int it = 0; it < niter; it++) {
    if (it + 1 < niter) {
      size_t go = (size_t)(it + 1) * 32;
      u16* dst = wpool + (buf ^ 1) * 1024;
      gl_lds16(gK0 + go * 256, dst);
      gl_lds16(gK1 + go * 256, dst + 512);
      gl_lds16(gV0 + go, dst + 2048);
      gl_lds16(gV1 + go, dst + 2048 + 512);
      __builtin_amdgcn_sched_barrier(0);
      __builtin_amdgcn_s_waitcnt(0x0F74);   // vmcnt <= 4: current buf landed
      __builtin_amdgcn_sched_barrier(0);
    } else {
      __builtin_amdgcn_sched_barrier(0);
      __builtin_amdgcn_s_waitcnt(0x0F70);   // vmcnt 0
      __builtin_amdgcn_sched_barrier(0);
    }
    const u16* bb = wpool + buf * 1024;
    U ka, kb, va, vb;
    ka.u = *(const uint4*)&bb[kA0];
    kb.u = *(const uint4*)&bb[kA1];
    va.u = *(const uint4*)&bb[vA0];
    vb.u = *(const uint4*)&bb[vA1];

    f32x4 z = {0.f, 0.f, 0.f, 0.f};
    f32x4 st0 = __builtin_amdgcn_mfma_f32_16x16x32_bf16(ka.s, qt.s, z, 0, 0, 0);
    f32x4 st1 = __builtin_amdgcn_mfma_f32_16x16x32_bf16(kb.s, qt.s, z, 0, 0, 0);

    // lane owns q=ql, keys kk0 + it*32 + quad*8 + {t*4+r}
    float s[8] = {st0[0], st0[1], st0[2], st0[3], st1[0], st1[1], st1[2], st1[3]};
    float cm = fmaxf(fmaxf(fmaxf(s[0], s[1]), fmaxf(s[2], s[3])),
                     fmaxf(fmaxf(s[4], s[5]), fmaxf(s[6], s[7])));
    cm = fmaxf(cm, __shfl_xor(cm, 16));
    cm = fmaxf(cm, __shfl_xor(cm, 32));
    float m_new = fmaxf(m_run, cm);
    float alpha = __expf(m_run - m_new);
    float p[8], ls = 0.f;
#pragma unroll
    for (int i = 0; i < 8; i++) { p[i] = __expf(s[i] - m_new); ls += p[i]; }
    ls += __shfl_xor(ls, 16);
    ls += __shfl_xor(ls, 32);
    l_run = l_run * alpha + ls;
    m_run = m_new;
#pragma unroll
    for (int r = 0; r < 4; r++) { o0[r] *= alpha; o1[r] *= alpha; }

    // P already in PV B-layout (keys quad*8+j): pack in-lane
    U pf;
    pf.u.x = (u32)f2bf(p[0]) | ((u32)f2bf(p[1]) << 16);
    pf.u.y = (u32)f2bf(p[2]) | ((u32)f2bf(p[3]) << 16);
    pf.u.z = (u32)f2bf(p[4]) | ((u32)f2bf(p[5]) << 16);
    pf.u.w = (u32)f2bf(p[6]) | ((u32)f2bf(p[7]) << 16);

    o0 = __builtin_amdgcn_mfma_f32_16x16x32_bf16(va.s, pf.s, o0, 0, 0, 0);
    o1 = __builtin_amdgcn_mfma_f32_16x16x32_bf16(vb.s, pf.s, o1, 0, 0, 0);
    buf ^= 1;
  }

  // ---- merge 4 wave-partials via LDS (overlays staging pool) ----
  __syncthreads();
  float* Of = (float*)pool;        // [4][32][16]
  float* mf = Of + 2048;           // [4][16]
  float* lf = mf + 64;             // [4][16]
#pragma unroll
  for (int r = 0; r < 4; r++) {
    Of[w * 512 + (quad * 4 + r) * 16 + ql] = o0[r];
    Of[w * 512 + (16 + quad * 4 + r) * 16 + ql] = o1[r];
  }
  if (quad == 0) { mf[w * 16 + ql] = m_run; lf[w * 16 + ql] = l_run; }
  __syncthreads();

#pragma unroll
  for (int half = 0; half < 2; half++) {
    int e = t + half * 256;
    int q = e >> 5, d = e & 31;
    float m0 = mf[q], m1 = mf[16 + q], m2 = mf[32 + q], m3 = mf[48 + q];
    float M = fmaxf(fmaxf(m0, m1), fmaxf(m2, m3));
    float c0 = __expf(m0 - M), c1 = __expf(m1 - M), c2 = __expf(m2 - M), c3 = __expf(m3 - M);
    float lt = c0 * lf[q] + c1 * lf[16 + q] + c2 * lf[32 + q] + c3 * lf[48 + q];
    int di = d * 16 + q;
    float v = c0 * Of[di] + c1 * Of[512 + di] + c2 * Of[1024 + di] + c3 * Of[1536 + di];
    Ot[((size_t)b * Pq + q0 + q) * DIM + h * HD + d] = f2bf(v / lt);
  }
}

extern "C" void kernel_launch(void* const* d_in, const int* in_sizes, int n_in,
                              void* d_out, int out_size, void* d_ws, size_t ws_size,
                              hipStream_t stream) {
  (void)in_sizes; (void)n_in; (void)out_size; (void)ws_size;
  u16* ws = (u16*)d_ws;
  int* flags = (int*)(ws + OFF_FLAGS);
  u16* cwx  = ws + OFF_CWX;
  u16* cbx  = ws + OFF_CBX;
  u16* cwy  = ws + OFF_CWY;
  u16* cby  = ws + OFF_CBY;
  u16* cwpx = ws + OFF_CWPX;
  u16* cbpx = ws + OFF_CBPX;
  u16* cwpy = ws + OFF_CWPY;
  u16* cbpy = ws + OFF_CBPY;
  u16* xt   = ws + OFF_XT;
  u16* yt   = ws + OFF_YT;
  u16* qktx = ws + OFF_QKTX;
  u16* qkty = ws + OFF_QKTY;
  u16* vcx  = ws + OFF_VCX;
  u16* vcy  = ws + OFF_VCY;
  u16* otx  = ws + OFF_OTX;
  u16* oty  = ws + OFF_OTY;

  k_detect<<<dim3(10), 256, 0, stream>>>(
      (const u16*)d_in[0], (const u16*)d_in[1], (const u16*)d_in[2], (const u16*)d_in[3],
      (const u16*)d_in[4], (const u16*)d_in[5], (const u16*)d_in[6], (const u16*)d_in[7],
      (const u16*)d_in[8], (const u16*)d_in[9], flags);
  k_convert<<<dim3(96, 8), 256, 0, stream>>>(
      d_in[2], d_in[3], d_in[4], d_in[5], d_in[6], d_in[7], d_in[8], d_in[9], ws, flags);
  k_xpose<<<dim3(PX / 32, CX / 32, B), 256, 0, stream>>>(d_in[0], xt, flags, 0, CX, PX);
  k_xpose<<<dim3(PY / 32, CY / 32, B), 256, 0, stream>>>(d_in[1], yt, flags, 1, CY, PY);

  k_mm<<<dim3(PX / 64, 6, B), 256, 0, stream>>>(
      cwx, xt, cbx, qktx, vcx, nullptr, nullptr, flags, 0, 0, CX, PX, 0);
  k_mm<<<dim3(PY / 64, 6, B), 256, 0, stream>>>(
      cwy, yt, cby, qkty, vcy, nullptr, nullptr, flags, 0, 0, CY, PY, 0);

  k_attn5<<<dim3(PX / 16, NH, B), 256, 0, stream>>>(qktx, qkty, vcy, otx, PX, PY);
  k_attn5<<<dim3(PY / 16, NH, B), 256, 0, stream>>>(qkty, qktx, vcx, oty, PY, PX);

  k_mm<<<dim3(PX / 64, CX / 64, B), 256, 0, stream>>>(
      cwpx, otx, cbpx, nullptr, nullptr, d_out, d_in[0], flags, 0, 0, DIM, PX, 1);
  k_mm<<<dim3(PY / 64, CY / 64, B), 256, 0, stream>>>(
      cwpy, oty, cbpy, nullptr, nullptr, d_out, d_in[1], flags, 1,
      (size_t)B * CX * PX, DIM, PY, 1);
}